// Round 7
// baseline (442.582 us; speedup 1.0000x reference)
//
#include <hip/hip_runtime.h>
#include <math.h>

namespace {
constexpr int D = 512;
constexpr int PE = 64;
constexpr int H = 8;
constexpr int DH = 64;
constexpr int INNER = 512;
constexpr int FF = 2048;
constexpr int B = 2;
constexpr int L = 2048;
constexpr int KN = 32;
constexpr int G = 128;
constexpr int LT = L + G;
constexpr float SCALE = 0.125f;

typedef unsigned short u16;
typedef unsigned short u16x8 __attribute__((ext_vector_type(8)));
typedef float f32x4 __attribute__((ext_vector_type(4)));
typedef _Float16 h2 __attribute__((ext_vector_type(2)));

#if defined(__has_builtin)
#if __has_builtin(__builtin_amdgcn_fdot2)
#define HAVE_FDOT2 1
#endif
#endif

__device__ __forceinline__ u16 f2bf(float x) {
  union { float f; unsigned u; } v;
  v.f = x;
  unsigned r = v.u + 0x7fffu + ((v.u >> 16) & 1u);
  return (u16)(r >> 16);
}

__device__ __forceinline__ float bf2f(u16 x) {
  union { unsigned u; float f; } v;
  v.u = ((unsigned)x) << 16;
  return v.f;
}

__device__ __forceinline__ u16 f2h(float x) {
  _Float16 h = (_Float16)x;
  return *(u16*)&h;
}

__device__ __forceinline__ unsigned pack2bf(float a, float b) {
  return (unsigned)f2bf(a) | ((unsigned)f2bf(b) << 16);
}

__device__ __forceinline__ float gelu_exact(float x) {
  return 0.5f * x * (1.0f + erff(x * 0.7071067811865475f));
}

__device__ __forceinline__ f32x4 mfma_16x16x32_bf16(u16x8 a, u16x8 b, f32x4 c) {
  asm("v_mfma_f32_16x16x32_bf16 %0, %1, %2, %0" : "+v"(c) : "v"(a), "v"(b));
  return c;
}

__device__ __forceinline__ float dot2h(h2 a, h2 b, float c) {
#ifdef HAVE_FDOT2
  return __builtin_amdgcn_fdot2(a, b, c, false);
#else
  return c + (float)a[0] * (float)b[0] + (float)a[1] * (float)b[1];
#endif
}

// Direct global->LDS DMA, 16B per lane. lds base must be wave-uniform;
// HW writes lds_base + lane*16. Global src address is per-lane.
__device__ __forceinline__ void gload_lds16(const u16* g, const u16* lds_base) {
  __builtin_amdgcn_global_load_lds(
      (const __attribute__((address_space(1))) unsigned int*)(uintptr_t)g,
      (__attribute__((address_space(3))) unsigned int*)(unsigned)(uintptr_t)lds_base,
      16, 0, 0);
}

__global__ __launch_bounds__(256) void split_kernel(const float* __restrict__ latents,
                                                    float* __restrict__ sp, float* __restrict__ gl) {
  int i = blockIdx.x * 256 + threadIdx.x;
  const int total = B * LT * D / 4;
  if (i >= total) return;
  float4 v = ((const float4*)latents)[i];
  int fi = i * 4;
  int d = fi % D;
  int row = fi / D;
  int l = row % LT;
  int b = row / LT;
  if (l < L) ((float4*)sp)[((size_t)(b * L + l) * D + d) / 4] = v;
  else ((float4*)gl)[((size_t)(b * G + (l - L)) * D + d) / 4] = v;
}

__global__ __launch_bounds__(256) void assemble_kernel(const float* __restrict__ sp,
                                                       const float* __restrict__ gl,
                                                       float* __restrict__ out) {
  int i = blockIdx.x * 256 + threadIdx.x;
  const int total = B * LT * D / 4;
  if (i >= total) return;
  int fi = i * 4;
  int d = fi % D;
  int row = fi / D;
  int l = row % LT;
  int b = row / LT;
  float4 v;
  if (l < L) v = ((const float4*)sp)[((size_t)(b * L + l) * D + d) / 4];
  else v = ((const float4*)gl)[((size_t)(b * G + (l - L)) * D + d) / 4];
  ((float4*)out)[i] = v;
}

// LayerNorm, bf16 output.
__global__ __launch_bounds__(256) void ln_kernel(const float* __restrict__ in,
                                                 const float* __restrict__ gw,
                                                 const float* __restrict__ bw,
                                                 u16* __restrict__ out) {
  int row = blockIdx.x;
  int t = threadIdx.x;
  const float* x = in + (size_t)row * D;
  float2 v = ((const float2*)x)[t];
  float s = v.x + v.y;
  float sq = v.x * v.x + v.y * v.y;
#pragma unroll
  for (int m = 1; m < 64; m <<= 1) {
    s += __shfl_xor(s, m, 64);
    sq += __shfl_xor(sq, m, 64);
  }
  __shared__ float ss[4], s2[4];
  int w = t >> 6;
  if ((t & 63) == 0) { ss[w] = s; s2[w] = sq; }
  __syncthreads();
  s = ss[0] + ss[1] + ss[2] + ss[3];
  sq = s2[0] + s2[1] + s2[2] + s2[3];
  float mean = s * (1.0f / D);
  float var = sq * (1.0f / D) - mean * mean;
  float rs = rsqrtf(var + 1e-5f);
  float2 gv = ((const float2*)gw)[t];
  float2 bv = ((const float2*)bw)[t];
  float ox = (v.x - mean) * rs * gv.x + bv.x;
  float oy = (v.y - mean) * rs * gv.y + bv.y;
  ((unsigned*)(out + (size_t)row * D))[t] = pack2bf(ox, oy);
}

// flat f32 -> bf16
__global__ __launch_bounds__(256) void cvt_bf16_kernel(const float* __restrict__ in,
                                                       u16* __restrict__ out, int n4) {
  int i = blockIdx.x * 256 + threadIdx.x;
  if (i >= n4) return;
  float4 v = ((const float4*)in)[i];
  ushort4 o;
  o.x = f2bf(v.x); o.y = f2bf(v.y); o.z = f2bf(v.z); o.w = f2bf(v.w);
  ((ushort4*)out)[i] = o;
}

// Transpose-convert weights: W fp32 [K][N] -> Wt bf16 [N][dstride] (cols 0..K-1 used).
struct WtJob { const float* src; u16* dst; int K; int N; int off; int dstride; };
struct WtJobs { WtJob j[16]; };

__global__ __launch_bounds__(256) void wt_convert_kernel(WtJobs jobs) {
  __shared__ float tile[32][33];
  int bid = blockIdx.x;
  int e = 0;
#pragma unroll
  for (int i = 1; i < 16; ++i) if (bid >= jobs.j[i].off) e = i;
  const WtJob& J = jobs.j[e];
  int ti = bid - J.off;
  int tiles_n = J.N >> 5;
  int tk = ti / tiles_n, tn = ti - tk * tiles_n;
  int t = threadIdx.x;
  int r = t >> 3, c4 = (t & 7) * 4;
  float4 v = *(const float4*)&J.src[(size_t)(tk * 32 + r) * J.N + tn * 32 + c4];
  tile[r][c4 + 0] = v.x; tile[r][c4 + 1] = v.y; tile[r][c4 + 2] = v.z; tile[r][c4 + 3] = v.w;
  __syncthreads();
  int r2 = t >> 3, k4 = (t & 7) * 4;
  ushort4 o;
  o.x = f2bf(tile[k4 + 0][r2]);
  o.y = f2bf(tile[k4 + 1][r2]);
  o.z = f2bf(tile[k4 + 2][r2]);
  o.w = f2bf(tile[k4 + 3][r2]);
  *(ushort4*)&J.dst[(size_t)(tn * 32 + r2) * J.dstride + tk * 32 + k4] = o;
}

// WQTt[(h*64+p)][c] = sum_d wkb[p][h*64+d] * wq[c][h*64+d]. grid (8h, 8ct).
__global__ __launch_bounds__(256) void comp_qt_kernel(const float* __restrict__ wq,
                                                      const float* __restrict__ wkb,
                                                      u16* __restrict__ out) {
  int h = blockIdx.x, ct = blockIdx.y;
  __shared__ float wk_s[64][68];  // [p][d]
  __shared__ float wq_s[64][68];  // [c][d]
  int t = threadIdx.x;
  int r = t >> 4, c4 = (t & 15) * 4;
#pragma unroll
  for (int i = 0; i < 4; ++i) {
    int rr = r + i * 16;
    *(float4*)&wk_s[rr][c4] = *(const float4*)&wkb[(size_t)rr * INNER + h * DH + c4];
    *(float4*)&wq_s[rr][c4] = *(const float4*)&wq[(size_t)(ct * 64 + rr) * INNER + h * DH + c4];
  }
  __syncthreads();
  int p = t >> 2, cb = (t & 3) * 16;
  float acc[16] = {};
  for (int d = 0; d < 64; ++d) {
    float a = wk_s[p][d];
#pragma unroll
    for (int j = 0; j < 16; ++j) acc[j] += a * wq_s[cb + j][d];
  }
  for (int j = 0; j < 16; ++j)
    out[(size_t)(h * 64 + p) * INNER + ct * 64 + cb + j] = f2bf(acc[j]);
}

// WO2t[j][512 + h*64 + p] = sum_d la_wo[h*64+d][j] * wvb[p][h*64+d]. grid (8h, 8jt).
__global__ __launch_bounds__(256) void comp_wo_kernel(const float* __restrict__ la_wo,
                                                      const float* __restrict__ wvb,
                                                      u16* __restrict__ WO2t) {
  int h = blockIdx.x, jt = blockIdx.y;
  __shared__ float lo_s[64][68];  // [d][j]
  __shared__ float wv_s[64][68];  // [p][d]
  int t = threadIdx.x;
  int r = t >> 4, c4 = (t & 15) * 4;
#pragma unroll
  for (int i = 0; i < 4; ++i) {
    int rr = r + i * 16;
    *(float4*)&lo_s[rr][c4] = *(const float4*)&la_wo[(size_t)(h * DH + rr) * D + jt * 64 + c4];
    *(float4*)&wv_s[rr][c4] = *(const float4*)&wvb[(size_t)rr * INNER + h * DH + c4];
  }
  __syncthreads();
  int j = t >> 2, pb = (t & 3) * 16;
  float acc[16] = {};
  for (int d = 0; d < 64; ++d) {
    float a = lo_s[d][j];
#pragma unroll
    for (int i = 0; i < 16; ++i) acc[i] += a * wv_s[pb + i][d];
  }
  for (int i = 0; i < 16; ++i)
    WO2t[(size_t)(jt * 64 + j) * 1024 + 512 + h * DH + pb + i] = f2bf(acc[i]);
}

// bf16 MFMA GEMM, double-buffered global_load_lds staging (T3 minimum 2-phase):
// STAGE(next) issued before compute(cur); single barrier per K-tile drains DMA.
// obf is a per-z 2-bit code: 0=f32, 1=bf16, 2=f32+bf16(out_bf), 3=fp16.
struct WSet { const u16* W[4]; void* out[4]; };

template <int BN>
__global__ __launch_bounds__(256) void gemm_bf16_kernel(const u16* __restrict__ A, WSet gs,
                                                        const float* __restrict__ bias,
                                                        const float* __restrict__ res,
                                                        u16* __restrict__ out_bf,
                                                        int M, int K, int N, int act, unsigned obf) {
  constexpr int NW = BN / 32;       // n-frags per wave
  __shared__ u16 As[2][128 * 64];   // [buf][row][64 k]
  __shared__ u16 Bs[2][BN * 64];
  int t = threadIdx.x;
  int wave = __builtin_amdgcn_readfirstlane(t >> 6);
  int lane = t & 63;
  int wr = wave >> 1, wc = wave & 1;
  int row16 = lane & 15, katom = lane >> 4;
  int bm = blockIdx.y * 128, bn = blockIdx.x * BN;
  const u16* W = gs.W[blockIdx.z];
  void* outp = gs.out[blockIdx.z];
  unsigned obz = (obf >> (blockIdx.z * 2)) & 3u;
  int srow = lane >> 3;   // row within 8-row staging call
  int sg = lane & 7;      // granule within 128B row
  int swz = row16 & 7;    // read-side granule XOR
  f32x4 acc[4][NW] = {};

  auto stage = [&](int buf, int kb) {
#pragma unroll
    for (int c = 0; c < 4; ++c) {
      int rowbase = wave * 32 + c * 8;
      int row = rowbase + srow;
      int gsrc = sg ^ (row & 7);
      gload_lds16(&A[(size_t)(bm + row) * K + kb + gsrc * 8], &As[buf][rowbase * 64]);
    }
#pragma unroll
    for (int c = 0; c < BN / 32; ++c) {
      int rowbase = wave * (BN / 4) + c * 8;
      int row = rowbase + srow;
      int gsrc = sg ^ (row & 7);
      gload_lds16(&W[(size_t)(bn + row) * K + kb + gsrc * 8], &Bs[buf][rowbase * 64]);
    }
  };

  stage(0, 0);
  __syncthreads();  // drains the DMA (vmcnt 0) + barrier
  int nk = K >> 6;
  int cur = 0;
  for (int ti = 0; ti < nk; ++ti) {
    if (ti + 1 < nk) stage(cur ^ 1, (ti + 1) << 6);  // prefetch overlaps MFMA below
#pragma unroll
    for (int kk = 0; kk < 2; ++kk) {
      u16x8 af[4], bf[NW];
#pragma unroll
      for (int m = 0; m < 4; ++m) {
        int r = wr * 64 + m * 16 + row16;
        af[m] = *(u16x8*)&As[cur][r * 64 + ((kk * 4 + katom) ^ swz) * 8];
      }
#pragma unroll
      for (int n = 0; n < NW; ++n) {
        int r = wc * (BN / 2) + n * 16 + row16;
        bf[n] = *(u16x8*)&Bs[cur][r * 64 + ((kk * 4 + katom) ^ swz) * 8];
      }
#pragma unroll
      for (int m = 0; m < 4; ++m)
#pragma unroll
        for (int n = 0; n < NW; ++n) acc[m][n] = mfma_16x16x32_bf16(af[m], bf[n], acc[m][n]);
    }
    __syncthreads();  // all waves done with cur; prefetch DMA drained
    cur ^= 1;
  }
#pragma unroll
  for (int m = 0; m < 4; ++m) {
    int row = bm + wr * 64 + m * 16 + katom * 4;
#pragma unroll
    for (int n = 0; n < NW; ++n) {
      int col = bn + wc * (BN / 2) + n * 16 + row16;
      float bsv = bias ? bias[col] : 0.f;
#pragma unroll
      for (int r = 0; r < 4; ++r) {
        float v = acc[m][n][r] + bsv;
        if (act) v = gelu_exact(v);
        size_t oi = (size_t)(row + r) * N + col;
        if (res) v += res[oi];
        if (obz == 1) ((u16*)outp)[oi] = f2bf(v);
        else if (obz == 3) ((u16*)outp)[oi] = f2h(v);
        else {
          ((float*)outp)[oi] = v;
          if (obz == 2) out_bf[oi] = f2bf(v);
        }
      }
    }
  }
}

// Local KNN attention v3: Q,TQ bf16; K,V fp16 (fdot2 / packed-fma math).
// Writes OA = [o_gather | ar] bf16.
__global__ __launch_bounds__(256) void local_attn2_kernel(
    const u16* __restrict__ Qh, const u16* __restrict__ Kh, const u16* __restrict__ Vh,
    const u16* __restrict__ TQh, const float* __restrict__ rpe, const float* __restrict__ dist,
    const int* __restrict__ idx, const float* __restrict__ lsig, u16* __restrict__ OA) {
  int blk = blockIdx.x;
  int b = blk >> 11;  // L = 2048
  int t = threadIdx.x;
  __shared__ _Float16 q_s[INNER];
  __shared__ float tq_s[INNER];  // [h*64+p]
  __shared__ float rpe_s[KN][68];
  __shared__ float a_s[H][KN + 1];
  __shared__ float ar_s[H][PE + 2];
  __shared__ int idx_s[KN];
  __shared__ float dist_s[KN];
  __shared__ float sig_s[H];
  size_t row = (size_t)blk;
  {
    unsigned qp = ((const unsigned*)(Qh + row * INNER))[t];
    q_s[2 * t] = (_Float16)bf2f((u16)qp);
    q_s[2 * t + 1] = (_Float16)bf2f((u16)(qp >> 16));
    unsigned tp = ((const unsigned*)(TQh + row * INNER))[t];
    tq_s[2 * t] = bf2f((u16)tp);
    tq_s[2 * t + 1] = bf2f((u16)(tp >> 16));
  }
  {
    const float* rp = rpe + row * (KN * PE);
    int k = t >> 3, p0 = (t & 7) * 8;
    *(float4*)&rpe_s[k][p0] = *(const float4*)&rp[k * PE + p0];
    *(float4*)&rpe_s[k][p0 + 4] = *(const float4*)&rp[k * PE + p0 + 4];
  }
  if (t < KN) {
    idx_s[t] = idx[row * KN + t];
    dist_s[t] = dist[row * KN + t];
  }
  if (t < H) sig_s[t] = expf(2.0f * lsig[t]);
  __syncthreads();
  {
    int h = t >> 5, k = t & 31;
    int rr = idx_s[k];
    const u16* krow = Kh + ((size_t)(b * L + rr)) * INNER + h * DH;  // fp16 data
    float acc = 0.f;
#pragma unroll
    for (int i = 0; i < 8; ++i) {
      u16x8 kv = *(const u16x8*)&krow[i * 8];
      u16x8 qv = *(const u16x8*)&q_s[h * DH + i * 8];
      const h2* kk = (const h2*)&kv;
      const h2* qq = (const h2*)&qv;
      acc = dot2h(kk[0], qq[0], acc);
      acc = dot2h(kk[1], qq[1], acc);
      acc = dot2h(kk[2], qq[2], acc);
      acc = dot2h(kk[3], qq[3], acc);
    }
    float accr = 0.f;
    const float* tqh = tq_s + h * DH;
#pragma unroll
    for (int p = 0; p < PE; p += 4) {
      float4 r4 = *(float4*)&rpe_s[k][p];
      float4 t4 = *(const float4*)&tqh[p];
      accr += r4.x * t4.x + r4.y * t4.y + r4.z * t4.z + r4.w * t4.w;
    }
    float dd = dist_s[k];
    float logit = SCALE * (acc + accr) - dd * dd / (2.0f * sig_s[h]);
    float mx = logit;
#pragma unroll
    for (int m = 1; m < 32; m <<= 1) mx = fmaxf(mx, __shfl_xor(mx, m, 64));
    float e = expf(logit - mx);
    float sum = e;
#pragma unroll
    for (int m = 1; m < 32; m <<= 1) sum += __shfl_xor(sum, m, 64);
    a_s[h][k] = e / sum;
  }
  __syncthreads();
  {
    int hh = t >> 6, p = t & 63;
    float acc0 = 0.f, acc1 = 0.f;
#pragma unroll
    for (int k = 0; k < KN; ++k) {
      float rv = rpe_s[k][p];
      acc0 += a_s[hh][k] * rv;
      acc1 += a_s[hh + 4][k] * rv;
    }
    ar_s[hh][p] = acc0;
    ar_s[hh + 4][p] = acc1;
  }
  __syncthreads();
  {
    int h0 = t >> 5;  // head of dims (2t, 2t+1)
    h2 o2;
    o2[0] = (_Float16)0.f;
    o2[1] = (_Float16)0.f;
#pragma unroll 8
    for (int k = 0; k < KN; ++k) {
      unsigned vv = *(const unsigned*)&Vh[((size_t)(b * L + idx_s[k])) * INNER + 2 * t];
      h2 v2 = *(h2*)&vv;
      _Float16 ah = (_Float16)a_s[h0][k];
      h2 a2;
      a2[0] = ah; a2[1] = ah;
      o2 = a2 * v2 + o2;  // v_pk_fma_f16
    }
    ((unsigned*)&OA[row * 1024])[t] = pack2bf((float)o2[0], (float)o2[1]);
    int p0 = 2 * (t & 31);
    ((unsigned*)&OA[row * 1024 + 512])[t] = pack2bf(ar_s[t >> 5][p0], ar_s[t >> 5][p0 + 1]);
  }
}

// spatial->global cross attention: block = (ltile of 32, h, b). Output bf16.
__global__ __launch_bounds__(256) void s2g_attn_kernel(const float* __restrict__ Q2,
                                                       const float* __restrict__ Kg,
                                                       const float* __restrict__ Vg,
                                                       u16* __restrict__ O) {
  int l0 = blockIdx.x * 32;
  int h = blockIdx.y;
  int b = blockIdx.z;
  int t = threadIdx.x;
  __shared__ float q_s[32][68];
  __shared__ float kv_s[128][68];
  __shared__ float lg[32][132];
  for (int i = t; i < 512; i += 256) {
    int r = i >> 4, c = (i & 15) * 4;
    *(float4*)&q_s[r][c] = *(const float4*)&Q2[((size_t)(b * L + l0 + r)) * INNER + h * DH + c];
  }
  for (int i = t; i < 2048; i += 256) {
    int r = i >> 4, c = (i & 15) * 4;
    *(float4*)&kv_s[r][c] = *(const float4*)&Kg[((size_t)(b * G + r)) * INNER + h * DH + c];
  }
  __syncthreads();
  int q = t >> 3, mg = t & 7;
  {
    float lv[16];
    float lmax = -1e30f;
#pragma unroll
    for (int i = 0; i < 16; ++i) {
      int m = mg + 8 * i;
      float acc = 0.f;
#pragma unroll
      for (int d = 0; d < DH; d += 4) {
        float4 kk = *(float4*)&kv_s[m][d];
        acc += kk.x * q_s[q][d] + kk.y * q_s[q][d + 1] + kk.z * q_s[q][d + 2] + kk.w * q_s[q][d + 3];
      }
      lv[i] = acc * SCALE;
      lmax = fmaxf(lmax, lv[i]);
    }
#pragma unroll
    for (int msk = 1; msk < 8; msk <<= 1) lmax = fmaxf(lmax, __shfl_xor(lmax, msk, 64));
    float lsum = 0.f;
#pragma unroll
    for (int i = 0; i < 16; ++i) {
      float e = expf(lv[i] - lmax);
      lv[i] = e;
      lsum += e;
    }
#pragma unroll
    for (int msk = 1; msk < 8; msk <<= 1) lsum += __shfl_xor(lsum, msk, 64);
    float inv = 1.0f / lsum;
#pragma unroll
    for (int i = 0; i < 16; ++i) lg[q][mg + 8 * i] = lv[i] * inv;
  }
  __syncthreads();
  for (int i = t; i < 2048; i += 256) {
    int r = i >> 4, c = (i & 15) * 4;
    *(float4*)&kv_s[r][c] = *(const float4*)&Vg[((size_t)(b * G + r)) * INNER + h * DH + c];
  }
  __syncthreads();
  {
    int dg = t & 7;
    float o[8] = {};
    for (int m = 0; m < G; ++m) {
      float w = lg[q][m];
      float4 v0 = *(float4*)&kv_s[m][dg * 8];
      float4 v1 = *(float4*)&kv_s[m][dg * 8 + 4];
      o[0] += w * v0.x; o[1] += w * v0.y; o[2] += w * v0.z; o[3] += w * v0.w;
      o[4] += w * v1.x; o[5] += w * v1.y; o[6] += w * v1.z; o[7] += w * v1.w;
    }
    size_t base = ((size_t)(b * L + l0 + q)) * INNER + h * DH + dg * 8;
    ushort4 s0, s1;
    s0.x = f2bf(o[0]); s0.y = f2bf(o[1]); s0.z = f2bf(o[2]); s0.w = f2bf(o[3]);
    s1.x = f2bf(o[4]); s1.y = f2bf(o[5]); s1.z = f2bf(o[6]); s1.w = f2bf(o[7]);
    *(ushort4*)&O[base] = s0;
    *(ushort4*)&O[base + 4] = s1;
  }
}

// ---------------- g2s: 5-phase MFMA pipeline ----------------
__global__ __launch_bounds__(256) void g2s_logits_kernel(const u16* __restrict__ QGh,
                                                         const u16* __restrict__ KBh,
                                                         float* __restrict__ LG) {
  __shared__ u16 Qs[128 * 72];
  __shared__ u16 Ks[128 * 72];
  int nt = blockIdx.x, h = blockIdx.y, b = blockIdx.z;
  int t = threadIdx.x;
  int wave = t >> 6, lane = t & 63;
  int row16 = lane & 15, katom = lane >> 4;
#pragma unroll
  for (int i = 0; i < 4; ++i) {
    int row = (t >> 3) + i * 32;
    int cg = t & 7;
    *(u16x8*)&Qs[row * 72 + cg * 8] =
        *(const u16x8*)&QGh[((size_t)(b * G + row)) * INNER + h * DH + cg * 8];
    *(u16x8*)&Ks[row * 72 + cg * 8] =
        *(const u16x8*)&KBh[((size_t)(b * L + nt * 128 + row)) * INNER + h * DH + cg * 8];
  }
  __syncthreads();
  f32x4 acc[2][8] = {};
#pragma unroll
  for (int kk = 0; kk < 2; ++kk) {
    u16x8 af[2], bf[8];
#pragma unroll
    for (int qt = 0; qt < 2; ++qt)
      af[qt] = *(u16x8*)&Qs[(wave * 32 + qt * 16 + row16) * 72 + kk * 32 + katom * 8];
#pragma unroll
    for (int nm = 0; nm < 8; ++nm)
      bf[nm] = *(u16x8*)&Ks[(nm * 16 + row16) * 72 + kk * 32 + katom * 8];
#pragma unroll
    for (int qt = 0; qt < 2; ++qt)
#pragma unroll
      for (int nm = 0; nm < 8; ++nm) acc[qt][nm] = mfma_16x16x32_bf16(af[qt], bf[nm], acc[qt][nm]);
  }
#pragma unroll
  for (int qt = 0; qt < 2; ++qt) {
    int g = wave * 32 + qt * 16 + katom * 4;
#pragma unroll
    for (int nm = 0; nm < 8; ++nm) {
      int m = nt * 128 + nm * 16 + row16;
#pragma unroll
      for (int r = 0; r < 4; ++r)
        LG[(((size_t)(b * H + h) * G) + g + r) * L + m] = acc[qt][nm][r] * SCALE;
    }
  }
}

__global__ __launch_bounds__(256) void g2s_softmax_kernel(const float* __restrict__ LG,
                                                          u16* __restrict__ WG) {
  int g = blockIdx.x & (G - 1);
  int b = blockIdx.x >> 7;
  int t = threadIdx.x;
  int w = t >> 6, lane = t & 63;
  __shared__ float red[8];
  for (int h = 0; h < H; ++h) {
    size_t base = (((size_t)(b * H + h) * G) + g) * L;
    float4 lo = *(const float4*)&LG[base + t * 8];
    float4 hi = *(const float4*)&LG[base + t * 8 + 4];
    float mx = fmaxf(fmaxf(fmaxf(lo.x, lo.y), fmaxf(lo.z, lo.w)),
                     fmaxf(fmaxf(hi.x, hi.y), fmaxf(hi.z, hi.w)));
#pragma unroll
    for (int m = 1; m < 64; m <<= 1) mx = fmaxf(mx, __shfl_xor(mx, m, 64));
    if (lane == 0) red[w] = mx;
    __syncthreads();
    mx = fmaxf(fmaxf(red[0], red[1]), fmaxf(red[2], red[3]));
    float e[8];
    e[0] = expf(lo.x - mx); e[1] = expf(lo.y - mx); e[2] = expf(lo.z - mx); e[3] = expf(lo.w - mx);
    e[4] = expf(hi.x - mx); e[5] = expf(hi.y - mx); e[6] = expf(hi.z - mx); e[7] = expf(hi.w - mx);
    float sum = e[0] + e[1] + e[2] + e[3] + e[4] + e[5] + e[6] + e[7];
#pragma unroll
    for (int m = 1; m < 64; m <<= 1) sum += __shfl_xor(sum, m, 64);
    if (lane == 0) red[4 + w] = sum;
    __syncthreads();
    float inv = 1.0f / (red[4] + red[5] + red[6] + red[7]);
    ushort4 o0, o1;
    o0.x = f2bf(e[0] * inv); o0.y = f2bf(e[1] * inv); o0.z = f2bf(e[2] * inv); o0.w = f2bf(e[3] * inv);
    o1.x = f2bf(e[4] * inv); o1.y = f2bf(e[5] * inv); o1.z = f2bf(e[6] * inv); o1.w = f2bf(e[7] * inv);
    *(ushort4*)&WG[base + t * 8] = o0;
    *(ushort4*)&WG[base + t * 8 + 4] = o1;
    __syncthreads();
  }
}

__global__ __launch_bounds__(256) void g2s_vt_kernel(const u16* __restrict__ VBh,
                                                     u16* __restrict__ Vt) {
  __shared__ u16 tile[32][36];
  int mt = blockIdx.x, ct = blockIdx.y, b = blockIdx.z;
  int t = threadIdx.x;
  int r = t >> 3, c4 = (t & 7) * 4;
  *(ushort4*)&tile[r][c4] =
      *(const ushort4*)&VBh[((size_t)(b * L + mt * 32 + r)) * INNER + ct * 32 + c4];
  __syncthreads();
  int r2 = t >> 3, m4 = (t & 7) * 4;
  int c = ct * 32 + r2;
  int h = c >> 6, d = c & 63;
  ushort4 o;
  o.x = tile[m4 + 0][r2]; o.y = tile[m4 + 1][r2]; o.z = tile[m4 + 2][r2]; o.w = tile[m4 + 3][r2];
  *(ushort4*)&Vt[(((size_t)(b * H + h) * DH) + d) * L + mt * 32 + m4] = o;
}

__global__ __launch_bounds__(256) void g2s_pv_kernel(const u16* __restrict__ WG,
                                                     const u16* __restrict__ Vt,
                                                     float* __restrict__ Opart) {
  __shared__ u16 Ws[128 * 40];
  __shared__ u16 Vs[64 * 40];
  int s = blockIdx.x, h = blockIdx.y, b = blockIdx.z;
  int t = threadIdx.x;
  int wave = t >> 6, lane = t & 63;
  int row16 = lane & 15, katom = lane >> 4;
  int r0 = t >> 2, cg = t & 3;
  size_t wbase = ((size_t)(b * H + h) * G) * L;
  size_t vbase = ((size_t)(b * H + h) * DH) * L;
  f32x4 acc[2][4] = {};
  for (int it = 0; it < 8; ++it) {
    int m0 = s * 256 + it * 32;
    u16x8 w0 = *(const u16x8*)&WG[wbase + (size_t)r0 * L + m0 + cg * 8];
    u16x8 w1 = *(const u16x8*)&WG[wbase + (size_t)(r0 + 64) * L + m0 + cg * 8];
    u16x8 v0 = *(const u16x8*)&Vt[vbase + (size_t)(t >> 2) * L + m0 + cg * 8];
    __syncthreads();
    *(u16x8*)&Ws[r0 * 40 + cg * 8] = w0;
    *(u16x8*)&Ws[(r0 + 64) * 40 + cg * 8] = w1;
    *(u16x8*)&Vs[(t >> 2) * 40 + cg * 8] = v0;
    __syncthreads();
    u16x8 af[2], bf[4];
#pragma unroll
    for (int qt = 0; qt < 2; ++qt)
      af[qt] = *(u16x8*)&Ws[(wave * 32 + qt * 16 + row16) * 40 + katom * 8];
#pragma unroll
    for (int nd = 0; nd < 4; ++nd)
      bf[nd] = *(u16x8*)&Vs[(nd * 16 + row16) * 40 + katom * 8];
#pragma unroll
    for (int qt = 0; qt < 2; ++qt)
#pragma unroll
      for (int nd = 0; nd < 4; ++nd) acc[qt][nd] = mfma_16x16x32_bf16(af[qt], bf[nd], acc[qt][nd]);
  }
  size_t obase = (((size_t)(b * H + h) * 8) + s) * G * DH;
#pragma unroll
  for (int qt = 0; qt < 2; ++qt) {
    int g = wave * 32 + qt * 16 + katom * 4;
#pragma unroll
    for (int nd = 0; nd < 4; ++nd) {
      int d = nd * 16 + row16;
#pragma unroll
      for (int r = 0; r < 4; ++r) Opart[obase + (size_t)(g + r) * DH + d] = acc[qt][nd][r];
    }
  }
}

__global__ __launch_bounds__(256) void g2s_combine_kernel(const float* __restrict__ Opart,
                                                          u16* __restrict__ OGh) {
  int g = blockIdx.x & (G - 1);
  int b = blockIdx.x >> 7;
  int t = threadIdx.x;
  int h = t >> 5, d0 = (t & 31) * 2;
  float o0 = 0.f, o1 = 0.f;
#pragma unroll
  for (int s = 0; s < 8; ++s) {
    const float* p = Opart + ((((size_t)(b * H + h) * 8) + s) * G + g) * DH + d0;
    o0 += p[0];
    o1 += p[1];
  }
  *(unsigned*)&OGh[((size_t)(b * G + g)) * INNER + h * DH + d0] = pack2bf(o0, o1);
}

}  // namespace

extern "C" void kernel_launch(void* const* d_in, const int* in_sizes, int n_in,
                              void* d_out, int out_size, void* d_ws, size_t ws_size,
                              hipStream_t stream) {
  (void)in_sizes; (void)n_in; (void)out_size; (void)ws_size;
  const float* latents = (const float*)d_in[0];
  const float* rpe = (const float*)d_in[1];
  const float* dist = (const float*)d_in[2];
  const float* sn_g = (const float*)d_in[3];
  const float* sn_b = (const float*)d_in[4];
  const float* la_wq = (const float*)d_in[5];
  const float* la_wk = (const float*)d_in[6];
  const float* la_wv = (const float*)d_in[7];
  const float* la_wo = (const float*)d_in[8];
  const float* la_bo = (const float*)d_in[9];
  const float* log_sigma = (const float*)d_in[10];
  const float* scn_g = (const float*)d_in[11];
  const float* scn_b = (const float*)d_in[12];
  const float* s2g_wq = (const float*)d_in[13];
  const float* s2g_wk = (const float*)d_in[14];
  const float* s2g_wv = (const float*)d_in[15];
  const float* s2g_wo = (const float*)d_in[16];
  const float* s2g_bo = (const float*)d_in[17];
  const float* gcn_g = (const float*)d_in[18];
  const float* gcn_b = (const float*)d_in[19];
  const float* g2s_wq = (const float*)d_in[20];
  const float* g2s_wk = (const float*)d_in[21];
  const float* g2s_wv = (const float*)d_in[22];
  const float* g2s_wo = (const float*)d_in[23];
  const float* g2s_bo = (const float*)d_in[24];
  const float* gfn_g = (const float*)d_in[25];
  const float* gfn_b = (const float*)d_in[26];
  const float* gff_w1 = (const float*)d_in[27];
  const float* gff_b1 = (const float*)d_in[28];
  const float* gff_w2 = (const float*)d_in[29];
  const float* gff_b2 = (const float*)d_in[30];
  const float* sfn_g = (const float*)d_in[31];
  const float* sfn_b = (const float*)d_in[32];
  const float* sff_w1 = (const float*)d_in[33];
  const float* sff_b1 = (const float*)d_in[34];
  const float* sff_w2 = (const float*)d_in[35];
  const float* sff_b2 = (const float*)d_in[36];
  const int* topk = (const int*)d_in[37];
  const float* wkb = la_wk + (size_t)D * INNER;  // rpe rows of wk
  const float* wvb = la_wv + (size_t)D * INNER;

  // ---- workspace layout ----
  char* wsb = (char*)d_ws;
  size_t off = 0;
  auto alloc = [&](size_t bytes) {
    char* p = wsb + off;
    off += (bytes + 255) & ~(size_t)255;
    return p;
  };
  const size_t SPn = (size_t)B * L * D;   // 2097152
  const size_t GLn = (size_t)B * G * D;   // 131072
  float* SP = (float*)alloc(SPn * 4);
  float* GL = (float*)alloc(GLn * 4);
  float* QB = (float*)alloc(SPn * 4);
  float* KB = (float*)alloc(SPn * 4);
  float* VB = (float*)alloc(SPn * 4);   // contiguous after KB
  float* S1 = (float*)alloc(SPn * 4);
  float* S2 = (float*)alloc(SPn * 4);
  float* G1 = (float*)alloc(GLn * 4);
  float* G2 = (float*)alloc(GLn * 4);
  float* QG = (float*)alloc(GLn * 4);
  float* KG = (float*)alloc(GLn * 4);
  float* VG = (float*)alloc(GLn * 4);
  u16* XNh = (u16*)alloc(SPn * 2);
  u16* OBh = (u16*)alloc(SPn * 2);
  u16* S2h = (u16*)alloc(SPn * 2);
  u16* HSh = (u16*)alloc((size_t)B * L * FF * 2);  // 16MB
  u16* GLh = (u16*)alloc(GLn * 2);
  u16* GNh = (u16*)alloc(GLn * 2);
  u16* OGh = (u16*)alloc(GLn * 2);
  u16* HGh = (u16*)alloc((size_t)B * G * FF * 2);
  const size_t SQ = 512 * 512, BIG = 512 * 2048;
  u16* WT = (u16*)alloc((12 * SQ + 4 * BIG) * 2);
  u16* la_wq_t = WT + 0 * SQ;
  u16* la_wk_t = WT + 1 * SQ;
  u16* la_wv_t = WT + 2 * SQ;
  u16* s2g_wq_t = WT + 4 * SQ;
  u16* s2g_wk_t = WT + 5 * SQ;
  u16* s2g_wv_t = WT + 6 * SQ;
  u16* s2g_wo_t = WT + 7 * SQ;
  u16* g2s_wq_t = WT + 8 * SQ;
  u16* g2s_wk_t = WT + 9 * SQ;
  u16* g2s_wv_t = WT + 10 * SQ;
  u16* g2s_wo_t = WT + 11 * SQ;
  u16* gff1_t = WT + 12 * SQ;
  u16* gff2_t = WT + 12 * SQ + BIG;
  u16* sff1_t = WT + 12 * SQ + 2 * BIG;
  u16* sff2_t = WT + 12 * SQ + 3 * BIG;
  u16* WQTt = (u16*)alloc(SQ * 2);          // composite tq weight [512][512]
  u16* WO2t = (u16*)alloc(512 * 1024 * 2);  // [512][1024]: [la_wo^T | Mt]

  // local-path bf16/fp16 aliases
  u16* lkh = (u16*)KB;          // fp16 K
  u16* lvh = (u16*)KB + SPn;    // fp16 V
  u16* ltqh = (u16*)VB;         // bf16 TQ
  u16* lqh = (u16*)VB + SPn;    // bf16 Q
  u16* OA = (u16*)QB;           // [B*L][1024] bf16

  // g2s aliases over dead regions (stream-sequential => safe)
  float* LG = KB;                 // 16MB spans KB+VB
  u16* WG = (u16*)S1;             // 8MB
  u16* KBh = (u16*)QB;            // 4MB
  u16* VBh = (u16*)QB + SPn;      // 4MB
  u16* QGh = HSh;
  u16* Vt = HSh + GLn;
  float* Opart = (float*)(HSh + GLn + (size_t)B * H * DH * L);

  const int threads = 256;
  int nsplit = (B * LT * D / 4 + 255) / 256;

  split_kernel<<<nsplit, threads, 0, stream>>>(latents, SP, GL);

  // ---- weight transpose-convert + composite weights ----
  {
    WtJobs jobs;
    auto set = [&](int i, const float* s, u16* d, int K, int N, int offv, int dstride) {
      jobs.j[i].src = s; jobs.j[i].dst = d; jobs.j[i].K = K; jobs.j[i].N = N;
      jobs.j[i].off = offv; jobs.j[i].dstride = dstride;
    };
    int o = 0;
    set(0, la_wq, la_wq_t, 512, 512, o, 512); o += 256;
    set(1, la_wk, la_wk_t, 512, 512, o, 512); o += 256;
    set(2, la_wv, la_wv_t, 512, 512, o, 512); o += 256;
    set(3, la_wo, WO2t, 512, 512, o, 1024); o += 256;  // first half of fused wo
    set(4, s2g_wq, s2g_wq_t, 512, 512, o, 512); o += 256;
    set(5, s2g_wk, s2g_wk_t, 512, 512, o, 512); o += 256;
    set(6, s2g_wv, s2g_wv_t, 512, 512, o, 512); o += 256;
    set(7, s2g_wo, s2g_wo_t, 512, 512, o, 512); o += 256;
    set(8, g2s_wq, g2s_wq_t, 512, 512, o, 512); o += 256;
    set(9, g2s_wk, g2s_wk_t, 512, 512, o, 512); o += 256;
    set(10, g2s_wv, g2s_wv_t, 512, 512, o, 512); o += 256;
    set(11, g2s_wo, g2s_wo_t, 512, 512, o, 512); o += 256;
    set(12, gff_w1, gff1_t, 512, 2048, o, 512); o += 1024;
    set(13, gff_w2, gff2_t, 2048, 512, o, 2048); o += 1024;
    set(14, sff_w1, sff1_t, 512, 2048, o, 512); o += 1024;
    set(15, sff_w2, sff2_t, 2048, 512, o, 2048); o += 1024;
    wt_convert_kernel<<<o, threads, 0, stream>>>(jobs);
  }
  comp_qt_kernel<<<dim3(8, 8), threads, 0, stream>>>(la_wq, wkb, WQTt);
  comp_wo_kernel<<<dim3(8, 8), threads, 0, stream>>>(la_wo, wvb, WO2t);

  auto gemm = [&](const u16* A, const u16* Wt, const float* bias, const float* res,
                  void* out, int M, int K, int N, int act, unsigned obf, u16* out_bf) {
    WSet gs{};
    gs.W[0] = Wt; gs.out[0] = out;
    if ((N / 128) * (M / 128) < 256 && (N % 64) == 0)
      gemm_bf16_kernel<64><<<dim3(N / 64, M / 128, 1), threads, 0, stream>>>(A, gs, bias, res, out_bf, M, K, N, act, obf);
    else
      gemm_bf16_kernel<128><<<dim3(N / 128, M / 128, 1), threads, 0, stream>>>(A, gs, bias, res, out_bf, M, K, N, act, obf);
  };
  auto gemm_multi = [&](const u16* A, const u16* W0, const u16* W1, const u16* W2, const u16* W3,
                        void* o0, void* o1, void* o2, void* o3, int nw, int M, int K, int N,
                        unsigned obf) {
    WSet gs{};
    gs.W[0] = W0; gs.W[1] = W1; gs.W[2] = W2; gs.W[3] = W3;
    gs.out[0] = o0; gs.out[1] = o1; gs.out[2] = o2; gs.out[3] = o3;
    gemm_bf16_kernel<128><<<dim3(N / 128, M / 128, nw), threads, 0, stream>>>(A, gs, nullptr, nullptr, nullptr, M, K, N, 0, obf);
  };

  // --- local KNN attention block ---
  ln_kernel<<<B * L, threads, 0, stream>>>(SP, sn_g, sn_b, XNh);
  // obf per z: Q bf16(1), K fp16(3), V fp16(3), TQ bf16(1)
  gemm_multi(XNh, la_wq_t, la_wk_t, la_wv_t, WQTt, lqh, lkh, lvh, ltqh, 4, B * L, D, INNER,
             1u | (3u << 2) | (3u << 4) | (1u << 6));
  local_attn2_kernel<<<B * L, threads, 0, stream>>>(lqh, lkh, lvh, ltqh, rpe, dist, topk,
                                                    log_sigma, OA);
  gemm(OA, WO2t, la_bo, SP, S1, B * L, 1024, D, 0, 0, nullptr);

  // --- spatial -> global cross attention ---
  ln_kernel<<<B * L, threads, 0, stream>>>(S1, scn_g, scn_b, XNh);
  gemm(XNh, s2g_wq_t, nullptr, nullptr, QB, B * L, D, INNER, 0, 0, nullptr);
  cvt_bf16_kernel<<<(int)(GLn / 4 + 255) / 256, threads, 0, stream>>>(GL, GLh, (int)(GLn / 4));
  gemm_multi(GLh, s2g_wk_t, s2g_wv_t, nullptr, nullptr, KG, VG, nullptr, nullptr, 2, B * G, D, INNER, 0);
  s2g_attn_kernel<<<dim3(L / 32, H, B), threads, 0, stream>>>(QB, KG, VG, OBh);
  gemm(OBh, s2g_wo_t, s2g_bo, S1, S2, B * L, INNER, D, 0, 2, S2h);  // dual write f32+bf16

  // --- global -> spatial cross attention (ctx = updated spatial S2) ---
  ln_kernel<<<B * G, threads, 0, stream>>>(GL, gcn_g, gcn_b, GNh);
  gemm(GNh, g2s_wq_t, nullptr, nullptr, QGh, B * G, D, INNER, 0, 1, nullptr);
  gemm_multi(S2h, g2s_wk_t, g2s_wv_t, nullptr, nullptr, KBh, VBh, nullptr, nullptr, 2, B * L, D, INNER,
             1u | (1u << 2));
  g2s_vt_kernel<<<dim3(L / 32, INNER / 32, B), threads, 0, stream>>>(VBh, Vt);
  g2s_logits_kernel<<<dim3(L / 128, H, B), threads, 0, stream>>>(QGh, KBh, LG);
  g2s_softmax_kernel<<<B * G, threads, 0, stream>>>(LG, WG);
  g2s_pv_kernel<<<dim3(8, H, B), threads, 0, stream>>>(WG, Vt, Opart);
  g2s_combine_kernel<<<B * G, threads, 0, stream>>>(Opart, OGh);
  gemm(OGh, g2s_wo_t, g2s_bo, GL, G1, B * G, INNER, D, 0, 0, nullptr);

  // --- global FFN ---
  ln_kernel<<<B * G, threads, 0, stream>>>(G1, gfn_g, gfn_b, GNh);
  gemm(GNh, gff1_t, gff_b1, nullptr, HGh, B * G, D, FF, 1, 1, nullptr);
  gemm(HGh, gff2_t, gff_b2, G1, G2, B * G, FF, D, 0, 0, nullptr);

  // --- spatial FFN ---
  ln_kernel<<<B * L, threads, 0, stream>>>(S2, sfn_g, sfn_b, XNh);
  gemm(XNh, sff1_t, sff_b1, nullptr, HSh, B * L, D, FF, 1, 1, nullptr);
  gemm(HSh, sff2_t, sff_b2, S2, S1, B * L, FF, D, 0, 0, nullptr);

  assemble_kernel<<<nsplit, threads, 0, stream>>>(S1, G2, (float*)d_out);
}

// Round 8
// 348.038 us; speedup vs baseline: 1.2716x; 1.2716x over previous
//
#include <hip/hip_runtime.h>
#include <math.h>

namespace {
constexpr int D = 512;
constexpr int PE = 64;
constexpr int H = 8;
constexpr int DH = 64;
constexpr int INNER = 512;
constexpr int FF = 2048;
constexpr int B = 2;
constexpr int L = 2048;
constexpr int KN = 32;
constexpr int G = 128;
constexpr int LT = L + G;
constexpr float SCALE = 0.125f;

typedef unsigned short u16;
typedef unsigned short u16x8 __attribute__((ext_vector_type(8)));
typedef float f32x4 __attribute__((ext_vector_type(4)));
typedef _Float16 h2 __attribute__((ext_vector_type(2)));

#if defined(__has_builtin)
#if __has_builtin(__builtin_amdgcn_fdot2)
#define HAVE_FDOT2 1
#endif
#endif

__device__ __forceinline__ u16 f2bf(float x) {
  union { float f; unsigned u; } v;
  v.f = x;
  unsigned r = v.u + 0x7fffu + ((v.u >> 16) & 1u);
  return (u16)(r >> 16);
}

__device__ __forceinline__ float bf2f(u16 x) {
  union { unsigned u; float f; } v;
  v.u = ((unsigned)x) << 16;
  return v.f;
}

__device__ __forceinline__ u16 f2h(float x) {
  _Float16 h = (_Float16)x;
  return *(u16*)&h;
}

__device__ __forceinline__ unsigned pack2bf(float a, float b) {
  return (unsigned)f2bf(a) | ((unsigned)f2bf(b) << 16);
}

__device__ __forceinline__ float gelu_exact(float x) {
  return 0.5f * x * (1.0f + erff(x * 0.7071067811865475f));
}

__device__ __forceinline__ f32x4 mfma_16x16x32_bf16(u16x8 a, u16x8 b, f32x4 c) {
  asm("v_mfma_f32_16x16x32_bf16 %0, %1, %2, %0" : "+v"(c) : "v"(a), "v"(b));
  return c;
}

__device__ __forceinline__ float dot2h(h2 a, h2 b, float c) {
#ifdef HAVE_FDOT2
  return __builtin_amdgcn_fdot2(a, b, c, false);
#else
  return c + (float)a[0] * (float)b[0] + (float)a[1] * (float)b[1];
#endif
}

// Direct global->LDS DMA, 16B per lane.
__device__ __forceinline__ void gload_lds16(const u16* g, const u16* lds_base) {
  __builtin_amdgcn_global_load_lds(
      (const __attribute__((address_space(1))) unsigned int*)(uintptr_t)g,
      (__attribute__((address_space(3))) unsigned int*)(unsigned)(uintptr_t)lds_base,
      16, 0, 0);
}

__global__ __launch_bounds__(256) void split_kernel(const float* __restrict__ latents,
                                                    float* __restrict__ sp, float* __restrict__ gl) {
  int i = blockIdx.x * 256 + threadIdx.x;
  const int total = B * LT * D / 4;
  if (i >= total) return;
  float4 v = ((const float4*)latents)[i];
  int fi = i * 4;
  int d = fi % D;
  int row = fi / D;
  int l = row % LT;
  int b = row / LT;
  if (l < L) ((float4*)sp)[((size_t)(b * L + l) * D + d) / 4] = v;
  else ((float4*)gl)[((size_t)(b * G + (l - L)) * D + d) / 4] = v;
}

__global__ __launch_bounds__(256) void assemble_kernel(const float* __restrict__ sp,
                                                       const float* __restrict__ gl,
                                                       float* __restrict__ out) {
  int i = blockIdx.x * 256 + threadIdx.x;
  const int total = B * LT * D / 4;
  if (i >= total) return;
  int fi = i * 4;
  int d = fi % D;
  int row = fi / D;
  int l = row % LT;
  int b = row / LT;
  float4 v;
  if (l < L) v = ((const float4*)sp)[((size_t)(b * L + l) * D + d) / 4];
  else v = ((const float4*)gl)[((size_t)(b * G + (l - L)) * D + d) / 4];
  ((float4*)out)[i] = v;
}

// LayerNorm, bf16 output.
__global__ __launch_bounds__(256) void ln_kernel(const float* __restrict__ in,
                                                 const float* __restrict__ gw,
                                                 const float* __restrict__ bw,
                                                 u16* __restrict__ out) {
  int row = blockIdx.x;
  int t = threadIdx.x;
  const float* x = in + (size_t)row * D;
  float2 v = ((const float2*)x)[t];
  float s = v.x + v.y;
  float sq = v.x * v.x + v.y * v.y;
#pragma unroll
  for (int m = 1; m < 64; m <<= 1) {
    s += __shfl_xor(s, m, 64);
    sq += __shfl_xor(sq, m, 64);
  }
  __shared__ float ss[4], s2[4];
  int w = t >> 6;
  if ((t & 63) == 0) { ss[w] = s; s2[w] = sq; }
  __syncthreads();
  s = ss[0] + ss[1] + ss[2] + ss[3];
  sq = s2[0] + s2[1] + s2[2] + s2[3];
  float mean = s * (1.0f / D);
  float var = sq * (1.0f / D) - mean * mean;
  float rs = rsqrtf(var + 1e-5f);
  float2 gv = ((const float2*)gw)[t];
  float2 bv = ((const float2*)bw)[t];
  float ox = (v.x - mean) * rs * gv.x + bv.x;
  float oy = (v.y - mean) * rs * gv.y + bv.y;
  ((unsigned*)(out + (size_t)row * D))[t] = pack2bf(ox, oy);
}

// flat f32 -> bf16
__global__ __launch_bounds__(256) void cvt_bf16_kernel(const float* __restrict__ in,
                                                       u16* __restrict__ out, int n4) {
  int i = blockIdx.x * 256 + threadIdx.x;
  if (i >= n4) return;
  float4 v = ((const float4*)in)[i];
  ushort4 o;
  o.x = f2bf(v.x); o.y = f2bf(v.y); o.z = f2bf(v.z); o.w = f2bf(v.w);
  ((ushort4*)out)[i] = o;
}

// Transpose-convert weights: W fp32 [K][N] -> Wt bf16 [N][dstride] (cols 0..K-1 used).
struct WtJob { const float* src; u16* dst; int K; int N; int off; int dstride; };
struct WtJobs { WtJob j[16]; };

__global__ __launch_bounds__(256) void wt_convert_kernel(WtJobs jobs) {
  __shared__ float tile[32][33];
  int bid = blockIdx.x;
  int e = 0;
#pragma unroll
  for (int i = 1; i < 16; ++i) if (bid >= jobs.j[i].off) e = i;
  const WtJob& J = jobs.j[e];
  int ti = bid - J.off;
  int tiles_n = J.N >> 5;
  int tk = ti / tiles_n, tn = ti - tk * tiles_n;
  int t = threadIdx.x;
  int r = t >> 3, c4 = (t & 7) * 4;
  float4 v = *(const float4*)&J.src[(size_t)(tk * 32 + r) * J.N + tn * 32 + c4];
  tile[r][c4 + 0] = v.x; tile[r][c4 + 1] = v.y; tile[r][c4 + 2] = v.z; tile[r][c4 + 3] = v.w;
  __syncthreads();
  int r2 = t >> 3, k4 = (t & 7) * 4;
  ushort4 o;
  o.x = f2bf(tile[k4 + 0][r2]);
  o.y = f2bf(tile[k4 + 1][r2]);
  o.z = f2bf(tile[k4 + 2][r2]);
  o.w = f2bf(tile[k4 + 3][r2]);
  *(ushort4*)&J.dst[(size_t)(tn * 32 + r2) * J.dstride + tk * 32 + k4] = o;
}

// WQTt[(h*64+p)][c] = sum_d wkb[p][h*64+d] * wq[c][h*64+d]. grid (8h, 8ct).
__global__ __launch_bounds__(256) void comp_qt_kernel(const float* __restrict__ wq,
                                                      const float* __restrict__ wkb,
                                                      u16* __restrict__ out) {
  int h = blockIdx.x, ct = blockIdx.y;
  __shared__ float wk_s[64][68];
  __shared__ float wq_s[64][68];
  int t = threadIdx.x;
  int r = t >> 4, c4 = (t & 15) * 4;
#pragma unroll
  for (int i = 0; i < 4; ++i) {
    int rr = r + i * 16;
    *(float4*)&wk_s[rr][c4] = *(const float4*)&wkb[(size_t)rr * INNER + h * DH + c4];
    *(float4*)&wq_s[rr][c4] = *(const float4*)&wq[(size_t)(ct * 64 + rr) * INNER + h * DH + c4];
  }
  __syncthreads();
  int p = t >> 2, cb = (t & 3) * 16;
  float acc[16] = {};
  for (int d = 0; d < 64; ++d) {
    float a = wk_s[p][d];
#pragma unroll
    for (int j = 0; j < 16; ++j) acc[j] += a * wq_s[cb + j][d];
  }
  for (int j = 0; j < 16; ++j)
    out[(size_t)(h * 64 + p) * INNER + ct * 64 + cb + j] = f2bf(acc[j]);
}

// WO2t[j][512 + h*64 + p] = sum_d la_wo[h*64+d][j] * wvb[p][h*64+d]. grid (8h, 8jt).
__global__ __launch_bounds__(256) void comp_wo_kernel(const float* __restrict__ la_wo,
                                                      const float* __restrict__ wvb,
                                                      u16* __restrict__ WO2t) {
  int h = blockIdx.x, jt = blockIdx.y;
  __shared__ float lo_s[64][68];
  __shared__ float wv_s[64][68];
  int t = threadIdx.x;
  int r = t >> 4, c4 = (t & 15) * 4;
#pragma unroll
  for (int i = 0; i < 4; ++i) {
    int rr = r + i * 16;
    *(float4*)&lo_s[rr][c4] = *(const float4*)&la_wo[(size_t)(h * DH + rr) * D + jt * 64 + c4];
    *(float4*)&wv_s[rr][c4] = *(const float4*)&wvb[(size_t)rr * INNER + h * DH + c4];
  }
  __syncthreads();
  int j = t >> 2, pb = (t & 3) * 16;
  float acc[16] = {};
  for (int d = 0; d < 64; ++d) {
    float a = lo_s[d][j];
#pragma unroll
    for (int i = 0; i < 16; ++i) acc[i] += a * wv_s[pb + i][d];
  }
  for (int i = 0; i < 16; ++i)
    WO2t[(size_t)(jt * 64 + j) * 1024 + 512 + h * DH + pb + i] = f2bf(acc[i]);
}

// bf16 MFMA GEMM v3: ds_read(cur)->regs FIRST, then DMA-prefetch(next), then MFMA.
// No LDS read follows the DMA inside an iteration, so the compiler's only
// vmcnt(0) is at the barrier -> prefetch overlaps the MFMA chain.
// obf: per-z 2-bit code: 0=f32, 1=bf16, 2=f32+bf16(out_bf), 3=fp16.
struct WSet { const u16* W[4]; void* out[4]; };

template <int BM, int BN>
__global__ __launch_bounds__(256) void gemm_v3_kernel(const u16* __restrict__ A, WSet gs,
                                                      const float* __restrict__ bias,
                                                      const float* __restrict__ res,
                                                      u16* __restrict__ out_bf,
                                                      int M, int K, int N, int act, unsigned obf) {
  constexpr int FM = BM / 32;  // frags per wave (wave grid 2x2)
  constexpr int FN = BN / 32;
  __shared__ u16 As[2][BM * 64];
  __shared__ u16 Bs[2][BN * 64];
  int t = threadIdx.x;
  int wave = __builtin_amdgcn_readfirstlane(t >> 6);
  int lane = t & 63;
  int wr = wave >> 1, wc = wave & 1;
  int row16 = lane & 15, katom = lane >> 4;
  int bm = blockIdx.y * BM, bn = blockIdx.x * BN;
  const u16* W = gs.W[blockIdx.z];
  void* outp = gs.out[blockIdx.z];
  unsigned obz = (obf >> (blockIdx.z * 2)) & 3u;
  int srow = lane >> 3;
  int sg = lane & 7;
  int swz = row16 & 7;
  f32x4 acc[FM][FN] = {};

  auto stage = [&](int buf, int kb) {
#pragma unroll
    for (int c = 0; c < BM / 32; ++c) {
      int rowbase = wave * (BM / 4) + c * 8;
      int row = rowbase + srow;
      int gsrc = sg ^ (row & 7);
      gload_lds16(&A[(size_t)(bm + row) * K + kb + gsrc * 8], &As[buf][rowbase * 64]);
    }
#pragma unroll
    for (int c = 0; c < BN / 32; ++c) {
      int rowbase = wave * (BN / 4) + c * 8;
      int row = rowbase + srow;
      int gsrc = sg ^ (row & 7);
      gload_lds16(&W[(size_t)(bn + row) * K + kb + gsrc * 8], &Bs[buf][rowbase * 64]);
    }
  };

  stage(0, 0);
  __syncthreads();  // drain prologue DMA
  int nk = K >> 6;
  int cur = 0;
  for (int ti = 0; ti < nk; ++ti) {
    // 1. LDS -> registers (both K=32 halves), before any new DMA is issued
    u16x8 af[2][FM], bf[2][FN];
#pragma unroll
    for (int kk = 0; kk < 2; ++kk) {
#pragma unroll
      for (int m = 0; m < FM; ++m) {
        int r = wr * (BM / 2) + m * 16 + row16;
        af[kk][m] = *(u16x8*)&As[cur][r * 64 + ((kk * 4 + katom) ^ swz) * 8];
      }
#pragma unroll
      for (int n = 0; n < FN; ++n) {
        int r = wc * (BN / 2) + n * 16 + row16;
        bf[kk][n] = *(u16x8*)&Bs[cur][r * 64 + ((kk * 4 + katom) ^ swz) * 8];
      }
    }
    __builtin_amdgcn_sched_barrier(0);  // keep ds_reads above the DMA issue
    // 2. issue prefetch of next K-tile (overlaps MFMA below)
    if (ti + 1 < nk) stage(cur ^ 1, (ti + 1) << 6);
    // 3. register-only MFMA chain
#pragma unroll
    for (int kk = 0; kk < 2; ++kk)
#pragma unroll
      for (int m = 0; m < FM; ++m)
#pragma unroll
        for (int n = 0; n < FN; ++n)
          acc[m][n] = mfma_16x16x32_bf16(af[kk][m], bf[kk][n], acc[m][n]);
    // 4. barrier (drains the prefetch DMA; next tile ready)
    __syncthreads();
    cur ^= 1;
  }
#pragma unroll
  for (int m = 0; m < FM; ++m) {
    int row = bm + wr * (BM / 2) + m * 16 + katom * 4;
#pragma unroll
    for (int n = 0; n < FN; ++n) {
      int col = bn + wc * (BN / 2) + n * 16 + row16;
      float bsv = bias ? bias[col] : 0.f;
#pragma unroll
      for (int r = 0; r < 4; ++r) {
        float v = acc[m][n][r] + bsv;
        if (act) v = gelu_exact(v);
        size_t oi = (size_t)(row + r) * N + col;
        if (res) v += res[oi];
        if (obz == 1) ((u16*)outp)[oi] = f2bf(v);
        else if (obz == 3) ((u16*)outp)[oi] = f2h(v);
        else {
          ((float*)outp)[oi] = v;
          if (obz == 2) out_bf[oi] = f2bf(v);
        }
      }
    }
  }
}

// Local KNN attention v3: Q,TQ bf16; K,V fp16. Writes OA = [o_gather | ar] bf16.
__global__ __launch_bounds__(256) void local_attn2_kernel(
    const u16* __restrict__ Qh, const u16* __restrict__ Kh, const u16* __restrict__ Vh,
    const u16* __restrict__ TQh, const float* __restrict__ rpe, const float* __restrict__ dist,
    const int* __restrict__ idx, const float* __restrict__ lsig, u16* __restrict__ OA) {
  int blk = blockIdx.x;
  int b = blk >> 11;
  int t = threadIdx.x;
  __shared__ _Float16 q_s[INNER];
  __shared__ float tq_s[INNER];
  __shared__ float rpe_s[KN][68];
  __shared__ float a_s[H][KN + 1];
  __shared__ float ar_s[H][PE + 2];
  __shared__ int idx_s[KN];
  __shared__ float dist_s[KN];
  __shared__ float sig_s[H];
  size_t row = (size_t)blk;
  {
    unsigned qp = ((const unsigned*)(Qh + row * INNER))[t];
    q_s[2 * t] = (_Float16)bf2f((u16)qp);
    q_s[2 * t + 1] = (_Float16)bf2f((u16)(qp >> 16));
    unsigned tp = ((const unsigned*)(TQh + row * INNER))[t];
    tq_s[2 * t] = bf2f((u16)tp);
    tq_s[2 * t + 1] = bf2f((u16)(tp >> 16));
  }
  {
    const float* rp = rpe + row * (KN * PE);
    int k = t >> 3, p0 = (t & 7) * 8;
    *(float4*)&rpe_s[k][p0] = *(const float4*)&rp[k * PE + p0];
    *(float4*)&rpe_s[k][p0 + 4] = *(const float4*)&rp[k * PE + p0 + 4];
  }
  if (t < KN) {
    idx_s[t] = idx[row * KN + t];
    dist_s[t] = dist[row * KN + t];
  }
  if (t < H) sig_s[t] = expf(2.0f * lsig[t]);
  __syncthreads();
  {
    int h = t >> 5, k = t & 31;
    int rr = idx_s[k];
    const u16* krow = Kh + ((size_t)(b * L + rr)) * INNER + h * DH;
    float acc = 0.f;
#pragma unroll
    for (int i = 0; i < 8; ++i) {
      u16x8 kv = *(const u16x8*)&krow[i * 8];
      u16x8 qv = *(const u16x8*)&q_s[h * DH + i * 8];
      const h2* kk = (const h2*)&kv;
      const h2* qq = (const h2*)&qv;
      acc = dot2h(kk[0], qq[0], acc);
      acc = dot2h(kk[1], qq[1], acc);
      acc = dot2h(kk[2], qq[2], acc);
      acc = dot2h(kk[3], qq[3], acc);
    }
    float accr = 0.f;
    const float* tqh = tq_s + h * DH;
#pragma unroll
    for (int p = 0; p < PE; p += 4) {
      float4 r4 = *(float4*)&rpe_s[k][p];
      float4 t4 = *(const float4*)&tqh[p];
      accr += r4.x * t4.x + r4.y * t4.y + r4.z * t4.z + r4.w * t4.w;
    }
    float dd = dist_s[k];
    float logit = SCALE * (acc + accr) - dd * dd / (2.0f * sig_s[h]);
    float mx = logit;
#pragma unroll
    for (int m = 1; m < 32; m <<= 1) mx = fmaxf(mx, __shfl_xor(mx, m, 64));
    float e = expf(logit - mx);
    float sum = e;
#pragma unroll
    for (int m = 1; m < 32; m <<= 1) sum += __shfl_xor(sum, m, 64);
    a_s[h][k] = e / sum;
  }
  __syncthreads();
  {
    int hh = t >> 6, p = t & 63;
    float acc0 = 0.f, acc1 = 0.f;
#pragma unroll
    for (int k = 0; k < KN; ++k) {
      float rv = rpe_s[k][p];
      acc0 += a_s[hh][k] * rv;
      acc1 += a_s[hh + 4][k] * rv;
    }
    ar_s[hh][p] = acc0;
    ar_s[hh + 4][p] = acc1;
  }
  __syncthreads();
  {
    int h0 = t >> 5;
    h2 o2;
    o2[0] = (_Float16)0.f;
    o2[1] = (_Float16)0.f;
#pragma unroll 8
    for (int k = 0; k < KN; ++k) {
      unsigned vv = *(const unsigned*)&Vh[((size_t)(b * L + idx_s[k])) * INNER + 2 * t];
      h2 v2 = *(h2*)&vv;
      _Float16 ah = (_Float16)a_s[h0][k];
      h2 a2;
      a2[0] = ah; a2[1] = ah;
      o2 = a2 * v2 + o2;
    }
    ((unsigned*)&OA[row * 1024])[t] = pack2bf((float)o2[0], (float)o2[1]);
    int p0 = 2 * (t & 31);
    ((unsigned*)&OA[row * 1024 + 512])[t] = pack2bf(ar_s[t >> 5][p0], ar_s[t >> 5][p0 + 1]);
  }
}

// spatial->global cross attention: block = (ltile of 32, h, b). Output bf16.
__global__ __launch_bounds__(256) void s2g_attn_kernel(const float* __restrict__ Q2,
                                                       const float* __restrict__ Kg,
                                                       const float* __restrict__ Vg,
                                                       u16* __restrict__ O) {
  int l0 = blockIdx.x * 32;
  int h = blockIdx.y;
  int b = blockIdx.z;
  int t = threadIdx.x;
  __shared__ float q_s[32][68];
  __shared__ float kv_s[128][68];
  __shared__ float lg[32][132];
  for (int i = t; i < 512; i += 256) {
    int r = i >> 4, c = (i & 15) * 4;
    *(float4*)&q_s[r][c] = *(const float4*)&Q2[((size_t)(b * L + l0 + r)) * INNER + h * DH + c];
  }
  for (int i = t; i < 2048; i += 256) {
    int r = i >> 4, c = (i & 15) * 4;
    *(float4*)&kv_s[r][c] = *(const float4*)&Kg[((size_t)(b * G + r)) * INNER + h * DH + c];
  }
  __syncthreads();
  int q = t >> 3, mg = t & 7;
  {
    float lv[16];
    float lmax = -1e30f;
#pragma unroll
    for (int i = 0; i < 16; ++i) {
      int m = mg + 8 * i;
      float acc = 0.f;
#pragma unroll
      for (int d = 0; d < DH; d += 4) {
        float4 kk = *(float4*)&kv_s[m][d];
        acc += kk.x * q_s[q][d] + kk.y * q_s[q][d + 1] + kk.z * q_s[q][d + 2] + kk.w * q_s[q][d + 3];
      }
      lv[i] = acc * SCALE;
      lmax = fmaxf(lmax, lv[i]);
    }
#pragma unroll
    for (int msk = 1; msk < 8; msk <<= 1) lmax = fmaxf(lmax, __shfl_xor(lmax, msk, 64));
    float lsum = 0.f;
#pragma unroll
    for (int i = 0; i < 16; ++i) {
      float e = expf(lv[i] - lmax);
      lv[i] = e;
      lsum += e;
    }
#pragma unroll
    for (int msk = 1; msk < 8; msk <<= 1) lsum += __shfl_xor(lsum, msk, 64);
    float inv = 1.0f / lsum;
#pragma unroll
    for (int i = 0; i < 16; ++i) lg[q][mg + 8 * i] = lv[i] * inv;
  }
  __syncthreads();
  for (int i = t; i < 2048; i += 256) {
    int r = i >> 4, c = (i & 15) * 4;
    *(float4*)&kv_s[r][c] = *(const float4*)&Vg[((size_t)(b * G + r)) * INNER + h * DH + c];
  }
  __syncthreads();
  {
    int dg = t & 7;
    float o[8] = {};
    for (int m = 0; m < G; ++m) {
      float w = lg[q][m];
      float4 v0 = *(float4*)&kv_s[m][dg * 8];
      float4 v1 = *(float4*)&kv_s[m][dg * 8 + 4];
      o[0] += w * v0.x; o[1] += w * v0.y; o[2] += w * v0.z; o[3] += w * v0.w;
      o[4] += w * v1.x; o[5] += w * v1.y; o[6] += w * v1.z; o[7] += w * v1.w;
    }
    size_t base = ((size_t)(b * L + l0 + q)) * INNER + h * DH + dg * 8;
    ushort4 s0, s1;
    s0.x = f2bf(o[0]); s0.y = f2bf(o[1]); s0.z = f2bf(o[2]); s0.w = f2bf(o[3]);
    s1.x = f2bf(o[4]); s1.y = f2bf(o[5]); s1.z = f2bf(o[6]); s1.w = f2bf(o[7]);
    *(ushort4*)&O[base] = s0;
    *(ushort4*)&O[base + 4] = s1;
  }
}

// ---------------- g2s: 5-phase MFMA pipeline ----------------
__global__ __launch_bounds__(256) void g2s_logits_kernel(const u16* __restrict__ QGh,
                                                         const u16* __restrict__ KBh,
                                                         float* __restrict__ LG) {
  __shared__ u16 Qs[128 * 72];
  __shared__ u16 Ks[128 * 72];
  int nt = blockIdx.x, h = blockIdx.y, b = blockIdx.z;
  int t = threadIdx.x;
  int wave = t >> 6, lane = t & 63;
  int row16 = lane & 15, katom = lane >> 4;
#pragma unroll
  for (int i = 0; i < 4; ++i) {
    int row = (t >> 3) + i * 32;
    int cg = t & 7;
    *(u16x8*)&Qs[row * 72 + cg * 8] =
        *(const u16x8*)&QGh[((size_t)(b * G + row)) * INNER + h * DH + cg * 8];
    *(u16x8*)&Ks[row * 72 + cg * 8] =
        *(const u16x8*)&KBh[((size_t)(b * L + nt * 128 + row)) * INNER + h * DH + cg * 8];
  }
  __syncthreads();
  f32x4 acc[2][8] = {};
#pragma unroll
  for (int kk = 0; kk < 2; ++kk) {
    u16x8 af[2], bf[8];
#pragma unroll
    for (int qt = 0; qt < 2; ++qt)
      af[qt] = *(u16x8*)&Qs[(wave * 32 + qt * 16 + row16) * 72 + kk * 32 + katom * 8];
#pragma unroll
    for (int nm = 0; nm < 8; ++nm)
      bf[nm] = *(u16x8*)&Ks[(nm * 16 + row16) * 72 + kk * 32 + katom * 8];
#pragma unroll
    for (int qt = 0; qt < 2; ++qt)
#pragma unroll
      for (int nm = 0; nm < 8; ++nm) acc[qt][nm] = mfma_16x16x32_bf16(af[qt], bf[nm], acc[qt][nm]);
  }
#pragma unroll
  for (int qt = 0; qt < 2; ++qt) {
    int g = wave * 32 + qt * 16 + katom * 4;
#pragma unroll
    for (int nm = 0; nm < 8; ++nm) {
      int m = nt * 128 + nm * 16 + row16;
#pragma unroll
      for (int r = 0; r < 4; ++r)
        LG[(((size_t)(b * H + h) * G) + g + r) * L + m] = acc[qt][nm][r] * SCALE;
    }
  }
}

__global__ __launch_bounds__(256) void g2s_softmax_kernel(const float* __restrict__ LG,
                                                          u16* __restrict__ WG) {
  int g = blockIdx.x & (G - 1);
  int b = blockIdx.x >> 7;
  int t = threadIdx.x;
  int w = t >> 6, lane = t & 63;
  __shared__ float red[8];
  for (int h = 0; h < H; ++h) {
    size_t base = (((size_t)(b * H + h) * G) + g) * L;
    float4 lo = *(const float4*)&LG[base + t * 8];
    float4 hi = *(const float4*)&LG[base + t * 8 + 4];
    float mx = fmaxf(fmaxf(fmaxf(lo.x, lo.y), fmaxf(lo.z, lo.w)),
                     fmaxf(fmaxf(hi.x, hi.y), fmaxf(hi.z, hi.w)));
#pragma unroll
    for (int m = 1; m < 64; m <<= 1) mx = fmaxf(mx, __shfl_xor(mx, m, 64));
    if (lane == 0) red[w] = mx;
    __syncthreads();
    mx = fmaxf(fmaxf(red[0], red[1]), fmaxf(red[2], red[3]));
    float e[8];
    e[0] = expf(lo.x - mx); e[1] = expf(lo.y - mx); e[2] = expf(lo.z - mx); e[3] = expf(lo.w - mx);
    e[4] = expf(hi.x - mx); e[5] = expf(hi.y - mx); e[6] = expf(hi.z - mx); e[7] = expf(hi.w - mx);
    float sum = e[0] + e[1] + e[2] + e[3] + e[4] + e[5] + e[6] + e[7];
#pragma unroll
    for (int m = 1; m < 64; m <<= 1) sum += __shfl_xor(sum, m, 64);
    if (lane == 0) red[4 + w] = sum;
    __syncthreads();
    float inv = 1.0f / (red[4] + red[5] + red[6] + red[7]);
    ushort4 o0, o1;
    o0.x = f2bf(e[0] * inv); o0.y = f2bf(e[1] * inv); o0.z = f2bf(e[2] * inv); o0.w = f2bf(e[3] * inv);
    o1.x = f2bf(e[4] * inv); o1.y = f2bf(e[5] * inv); o1.z = f2bf(e[6] * inv); o1.w = f2bf(e[7] * inv);
    *(ushort4*)&WG[base + t * 8] = o0;
    *(ushort4*)&WG[base + t * 8 + 4] = o1;
    __syncthreads();
  }
}

__global__ __launch_bounds__(256) void g2s_vt_kernel(const u16* __restrict__ VBh,
                                                     u16* __restrict__ Vt) {
  __shared__ u16 tile[32][36];
  int mt = blockIdx.x, ct = blockIdx.y, b = blockIdx.z;
  int t = threadIdx.x;
  int r = t >> 3, c4 = (t & 7) * 4;
  *(ushort4*)&tile[r][c4] =
      *(const ushort4*)&VBh[((size_t)(b * L + mt * 32 + r)) * INNER + ct * 32 + c4];
  __syncthreads();
  int r2 = t >> 3, m4 = (t & 7) * 4;
  int c = ct * 32 + r2;
  int h = c >> 6, d = c & 63;
  ushort4 o;
  o.x = tile[m4 + 0][r2]; o.y = tile[m4 + 1][r2]; o.z = tile[m4 + 2][r2]; o.w = tile[m4 + 3][r2];
  *(ushort4*)&Vt[(((size_t)(b * H + h) * DH) + d) * L + mt * 32 + m4] = o;
}

__global__ __launch_bounds__(256) void g2s_pv_kernel(const u16* __restrict__ WG,
                                                     const u16* __restrict__ Vt,
                                                     float* __restrict__ Opart) {
  __shared__ u16 Ws[128 * 40];
  __shared__ u16 Vs[64 * 40];
  int s = blockIdx.x, h = blockIdx.y, b = blockIdx.z;
  int t = threadIdx.x;
  int wave = t >> 6, lane = t & 63;
  int row16 = lane & 15, katom = lane >> 4;
  int r0 = t >> 2, cg = t & 3;
  size_t wbase = ((size_t)(b * H + h) * G) * L;
  size_t vbase = ((size_t)(b * H + h) * DH) * L;
  f32x4 acc[2][4] = {};
  for (int it = 0; it < 8; ++it) {
    int m0 = s * 256 + it * 32;
    u16x8 w0 = *(const u16x8*)&WG[wbase + (size_t)r0 * L + m0 + cg * 8];
    u16x8 w1 = *(const u16x8*)&WG[wbase + (size_t)(r0 + 64) * L + m0 + cg * 8];
    u16x8 v0 = *(const u16x8*)&Vt[vbase + (size_t)(t >> 2) * L + m0 + cg * 8];
    __syncthreads();
    *(u16x8*)&Ws[r0 * 40 + cg * 8] = w0;
    *(u16x8*)&Ws[(r0 + 64) * 40 + cg * 8] = w1;
    *(u16x8*)&Vs[(t >> 2) * 40 + cg * 8] = v0;
    __syncthreads();
    u16x8 af[2], bf[4];
#pragma unroll
    for (int qt = 0; qt < 2; ++qt)
      af[qt] = *(u16x8*)&Ws[(wave * 32 + qt * 16 + row16) * 40 + katom * 8];
#pragma unroll
    for (int nd = 0; nd < 4; ++nd)
      bf[nd] = *(u16x8*)&Vs[(nd * 16 + row16) * 40 + katom * 8];
#pragma unroll
    for (int qt = 0; qt < 2; ++qt)
#pragma unroll
      for (int nd = 0; nd < 4; ++nd) acc[qt][nd] = mfma_16x16x32_bf16(af[qt], bf[nd], acc[qt][nd]);
  }
  size_t obase = (((size_t)(b * H + h) * 8) + s) * G * DH;
#pragma unroll
  for (int qt = 0; qt < 2; ++qt) {
    int g = wave * 32 + qt * 16 + katom * 4;
#pragma unroll
    for (int nd = 0; nd < 4; ++nd) {
      int d = nd * 16 + row16;
#pragma unroll
      for (int r = 0; r < 4; ++r) Opart[obase + (size_t)(g + r) * DH + d] = acc[qt][nd][r];
    }
  }
}

__global__ __launch_bounds__(256) void g2s_combine_kernel(const float* __restrict__ Opart,
                                                          u16* __restrict__ OGh) {
  int g = blockIdx.x & (G - 1);
  int b = blockIdx.x >> 7;
  int t = threadIdx.x;
  int h = t >> 5, d0 = (t & 31) * 2;
  float o0 = 0.f, o1 = 0.f;
#pragma unroll
  for (int s = 0; s < 8; ++s) {
    const float* p = Opart + ((((size_t)(b * H + h) * 8) + s) * G + g) * DH + d0;
    o0 += p[0];
    o1 += p[1];
  }
  *(unsigned*)&OGh[((size_t)(b * G + g)) * INNER + h * DH + d0] = pack2bf(o0, o1);
}

}  // namespace

extern "C" void kernel_launch(void* const* d_in, const int* in_sizes, int n_in,
                              void* d_out, int out_size, void* d_ws, size_t ws_size,
                              hipStream_t stream) {
  (void)in_sizes; (void)n_in; (void)out_size; (void)ws_size;
  const float* latents = (const float*)d_in[0];
  const float* rpe = (const float*)d_in[1];
  const float* dist = (const float*)d_in[2];
  const float* sn_g = (const float*)d_in[3];
  const float* sn_b = (const float*)d_in[4];
  const float* la_wq = (const float*)d_in[5];
  const float* la_wk = (const float*)d_in[6];
  const float* la_wv = (const float*)d_in[7];
  const float* la_wo = (const float*)d_in[8];
  const float* la_bo = (const float*)d_in[9];
  const float* log_sigma = (const float*)d_in[10];
  const float* scn_g = (const float*)d_in[11];
  const float* scn_b = (const float*)d_in[12];
  const float* s2g_wq = (const float*)d_in[13];
  const float* s2g_wk = (const float*)d_in[14];
  const float* s2g_wv = (const float*)d_in[15];
  const float* s2g_wo = (const float*)d_in[16];
  const float* s2g_bo = (const float*)d_in[17];
  const float* gcn_g = (const float*)d_in[18];
  const float* gcn_b = (const float*)d_in[19];
  const float* g2s_wq = (const float*)d_in[20];
  const float* g2s_wk = (const float*)d_in[21];
  const float* g2s_wv = (const float*)d_in[22];
  const float* g2s_wo = (const float*)d_in[23];
  const float* g2s_bo = (const float*)d_in[24];
  const float* gfn_g = (const float*)d_in[25];
  const float* gfn_b = (const float*)d_in[26];
  const float* gff_w1 = (const float*)d_in[27];
  const float* gff_b1 = (const float*)d_in[28];
  const float* gff_w2 = (const float*)d_in[29];
  const float* gff_b2 = (const float*)d_in[30];
  const float* sfn_g = (const float*)d_in[31];
  const float* sfn_b = (const float*)d_in[32];
  const float* sff_w1 = (const float*)d_in[33];
  const float* sff_b1 = (const float*)d_in[34];
  const float* sff_w2 = (const float*)d_in[35];
  const float* sff_b2 = (const float*)d_in[36];
  const int* topk = (const int*)d_in[37];
  const float* wkb = la_wk + (size_t)D * INNER;
  const float* wvb = la_wv + (size_t)D * INNER;

  // ---- workspace layout ----
  char* wsb = (char*)d_ws;
  size_t off = 0;
  auto alloc = [&](size_t bytes) {
    char* p = wsb + off;
    off += (bytes + 255) & ~(size_t)255;
    return p;
  };
  const size_t SPn = (size_t)B * L * D;
  const size_t GLn = (size_t)B * G * D;
  float* SP = (float*)alloc(SPn * 4);
  float* GL = (float*)alloc(GLn * 4);
  float* QB = (float*)alloc(SPn * 4);
  float* KB = (float*)alloc(SPn * 4);
  float* VB = (float*)alloc(SPn * 4);
  float* S1 = (float*)alloc(SPn * 4);
  float* S2 = (float*)alloc(SPn * 4);
  float* G1 = (float*)alloc(GLn * 4);
  float* G2 = (float*)alloc(GLn * 4);
  float* QG = (float*)alloc(GLn * 4);
  float* KG = (float*)alloc(GLn * 4);
  float* VG = (float*)alloc(GLn * 4);
  u16* XNh = (u16*)alloc(SPn * 2);
  u16* OBh = (u16*)alloc(SPn * 2);
  u16* S2h = (u16*)alloc(SPn * 2);
  u16* HSh = (u16*)alloc((size_t)B * L * FF * 2);
  u16* GLh = (u16*)alloc(GLn * 2);
  u16* GNh = (u16*)alloc(GLn * 2);
  u16* OGh = (u16*)alloc(GLn * 2);
  u16* HGh = (u16*)alloc((size_t)B * G * FF * 2);
  const size_t SQ = 512 * 512, BIG = 512 * 2048;
  u16* WT = (u16*)alloc((12 * SQ + 4 * BIG) * 2);
  u16* la_wq_t = WT + 0 * SQ;
  u16* la_wk_t = WT + 1 * SQ;
  u16* la_wv_t = WT + 2 * SQ;
  u16* s2g_wq_t = WT + 4 * SQ;
  u16* s2g_wk_t = WT + 5 * SQ;
  u16* s2g_wv_t = WT + 6 * SQ;
  u16* s2g_wo_t = WT + 7 * SQ;
  u16* g2s_wq_t = WT + 8 * SQ;
  u16* g2s_wk_t = WT + 9 * SQ;
  u16* g2s_wv_t = WT + 10 * SQ;
  u16* g2s_wo_t = WT + 11 * SQ;
  u16* gff1_t = WT + 12 * SQ;
  u16* gff2_t = WT + 12 * SQ + BIG;
  u16* sff1_t = WT + 12 * SQ + 2 * BIG;
  u16* sff2_t = WT + 12 * SQ + 3 * BIG;
  u16* WQTt = (u16*)alloc(SQ * 2);
  u16* WO2t = (u16*)alloc(512 * 1024 * 2);

  // local-path bf16/fp16 aliases
  u16* lkh = (u16*)KB;
  u16* lvh = (u16*)KB + SPn;
  u16* ltqh = (u16*)VB;
  u16* lqh = (u16*)VB + SPn;
  u16* OA = (u16*)QB;

  // g2s aliases over dead regions (stream-sequential => safe)
  float* LG = KB;
  u16* WG = (u16*)S1;
  u16* KBh = (u16*)QB;
  u16* VBh = (u16*)QB + SPn;
  u16* QGh = HSh;
  u16* Vt = HSh + GLn;
  float* Opart = (float*)(HSh + GLn + (size_t)B * H * DH * L);

  const int threads = 256;
  int nsplit = (B * LT * D / 4 + 255) / 256;

  split_kernel<<<nsplit, threads, 0, stream>>>(latents, SP, GL);

  // ---- weight transpose-convert + composite weights ----
  {
    WtJobs jobs;
    auto set = [&](int i, const float* s, u16* d, int K, int N, int offv, int dstride) {
      jobs.j[i].src = s; jobs.j[i].dst = d; jobs.j[i].K = K; jobs.j[i].N = N;
      jobs.j[i].off = offv; jobs.j[i].dstride = dstride;
    };
    int o = 0;
    set(0, la_wq, la_wq_t, 512, 512, o, 512); o += 256;
    set(1, la_wk, la_wk_t, 512, 512, o, 512); o += 256;
    set(2, la_wv, la_wv_t, 512, 512, o, 512); o += 256;
    set(3, la_wo, WO2t, 512, 512, o, 1024); o += 256;
    set(4, s2g_wq, s2g_wq_t, 512, 512, o, 512); o += 256;
    set(5, s2g_wk, s2g_wk_t, 512, 512, o, 512); o += 256;
    set(6, s2g_wv, s2g_wv_t, 512, 512, o, 512); o += 256;
    set(7, s2g_wo, s2g_wo_t, 512, 512, o, 512); o += 256;
    set(8, g2s_wq, g2s_wq_t, 512, 512, o, 512); o += 256;
    set(9, g2s_wk, g2s_wk_t, 512, 512, o, 512); o += 256;
    set(10, g2s_wv, g2s_wv_t, 512, 512, o, 512); o += 256;
    set(11, g2s_wo, g2s_wo_t, 512, 512, o, 512); o += 256;
    set(12, gff_w1, gff1_t, 512, 2048, o, 512); o += 1024;
    set(13, gff_w2, gff2_t, 2048, 512, o, 2048); o += 1024;
    set(14, sff_w1, sff1_t, 512, 2048, o, 512); o += 1024;
    set(15, sff_w2, sff2_t, 2048, 512, o, 2048); o += 1024;
    wt_convert_kernel<<<o, threads, 0, stream>>>(jobs);
  }
  comp_qt_kernel<<<dim3(8, 8), threads, 0, stream>>>(la_wq, wkb, WQTt);
  comp_wo_kernel<<<dim3(8, 8), threads, 0, stream>>>(la_wo, wvb, WO2t);

  auto gemm = [&](const u16* A, const u16* Wt, const float* bias, const float* res,
                  void* out, int M, int K, int N, int act, unsigned obf, u16* out_bf) {
    WSet gs{};
    gs.W[0] = Wt; gs.out[0] = out;
    if (N >= 1024)
      gemm_v3_kernel<64, 128><<<dim3(N / 128, M / 64, 1), threads, 0, stream>>>(
          A, gs, bias, res, out_bf, M, K, N, act, obf);
    else
      gemm_v3_kernel<64, 64><<<dim3(N / 64, M / 64, 1), threads, 0, stream>>>(
          A, gs, bias, res, out_bf, M, K, N, act, obf);
  };
  auto gemm_multi = [&](const u16* A, const u16* W0, const u16* W1, const u16* W2, const u16* W3,
                        void* o0, void* o1, void* o2, void* o3, int nw, int M, int K, int N,
                        unsigned obf) {
    WSet gs{};
    gs.W[0] = W0; gs.W[1] = W1; gs.W[2] = W2; gs.W[3] = W3;
    gs.out[0] = o0; gs.out[1] = o1; gs.out[2] = o2; gs.out[3] = o3;
    gemm_v3_kernel<64, 64><<<dim3(N / 64, M / 64, nw), threads, 0, stream>>>(
        A, gs, nullptr, nullptr, nullptr, M, K, N, 0, obf);
  };

  // --- local KNN attention block ---
  ln_kernel<<<B * L, threads, 0, stream>>>(SP, sn_g, sn_b, XNh);
  // obf per z: Q bf16(1), K fp16(3), V fp16(3), TQ bf16(1)
  gemm_multi(XNh, la_wq_t, la_wk_t, la_wv_t, WQTt, lqh, lkh, lvh, ltqh, 4, B * L, D, INNER,
             1u | (3u << 2) | (3u << 4) | (1u << 6));
  local_attn2_kernel<<<B * L, threads, 0, stream>>>(lqh, lkh, lvh, ltqh, rpe, dist, topk,
                                                    log_sigma, OA);
  gemm(OA, WO2t, la_bo, SP, S1, B * L, 1024, D, 0, 0, nullptr);

  // --- spatial -> global cross attention ---
  ln_kernel<<<B * L, threads, 0, stream>>>(S1, scn_g, scn_b, XNh);
  gemm(XNh, s2g_wq_t, nullptr, nullptr, QB, B * L, D, INNER, 0, 0, nullptr);
  cvt_bf16_kernel<<<(int)(GLn / 4 + 255) / 256, threads, 0, stream>>>(GL, GLh, (int)(GLn / 4));
  gemm_multi(GLh, s2g_wk_t, s2g_wv_t, nullptr, nullptr, KG, VG, nullptr, nullptr, 2, B * G, D, INNER, 0);
  s2g_attn_kernel<<<dim3(L / 32, H, B), threads, 0, stream>>>(QB, KG, VG, OBh);
  gemm(OBh, s2g_wo_t, s2g_bo, S1, S2, B * L, INNER, D, 0, 2, S2h);  // dual write f32+bf16

  // --- global -> spatial cross attention (ctx = updated spatial S2) ---
  ln_kernel<<<B * G, threads, 0, stream>>>(GL, gcn_g, gcn_b, GNh);
  gemm(GNh, g2s_wq_t, nullptr, nullptr, QGh, B * G, D, INNER, 0, 1, nullptr);
  gemm_multi(S2h, g2s_wk_t, g2s_wv_t, nullptr, nullptr, KBh, VBh, nullptr, nullptr, 2, B * L, D, INNER,
             1u | (1u << 2));
  g2s_vt_kernel<<<dim3(L / 32, INNER / 32, B), threads, 0, stream>>>(VBh, Vt);
  g2s_logits_kernel<<<dim3(L / 128, H, B), threads, 0, stream>>>(QGh, KBh, LG);
  g2s_softmax_kernel<<<B * G, threads, 0, stream>>>(LG, WG);
  g2s_pv_kernel<<<dim3(8, H, B), threads, 0, stream>>>(WG, Vt, Opart);
  g2s_combine_kernel<<<B * G, threads, 0, stream>>>(Opart, OGh);
  gemm(OGh, g2s_wo_t, g2s_bo, GL, G1, B * G, INNER, D, 0, 0, nullptr);

  // --- global FFN ---
  ln_kernel<<<B * G, threads, 0, stream>>>(G1, gfn_g, gfn_b, GNh);
  gemm(GNh, gff1_t, gff_b1, nullptr, HGh, B * G, D, FF, 1, 1, nullptr);
  gemm(HGh, gff2_t, gff_b2, G1, G2, B * G, FF, D, 0, 0, nullptr);

  // --- spatial FFN ---
  ln_kernel<<<B * L, threads, 0, stream>>>(S2, sfn_g, sfn_b, XNh);
  gemm(XNh, sff1_t, sff_b1, nullptr, HSh, B * L, D, FF, 1, 1, nullptr);
  gemm(HSh, sff2_t, sff_b2, S2, S1, B * L, FF, D, 0, 0, nullptr);

  assemble_kernel<<<nsplit, threads, 0, stream>>>(S1, G2, (float*)d_out);
}

// Round 9
// 322.421 us; speedup vs baseline: 1.3727x; 1.0795x over previous
//
#include <hip/hip_runtime.h>
#include <math.h>

namespace {
constexpr int D = 512;
constexpr int PE = 64;
constexpr int H = 8;
constexpr int DH = 64;
constexpr int INNER = 512;
constexpr int FF = 2048;
constexpr int B = 2;
constexpr int L = 2048;
constexpr int KN = 32;
constexpr int G = 128;
constexpr int LT = L + G;
constexpr float SCALE = 0.125f;

typedef unsigned short u16;
typedef unsigned short u16x8 __attribute__((ext_vector_type(8)));
typedef float f32x4 __attribute__((ext_vector_type(4)));
typedef _Float16 h2 __attribute__((ext_vector_type(2)));

#if defined(__has_builtin)
#if __has_builtin(__builtin_amdgcn_fdot2)
#define HAVE_FDOT2 1
#endif
#endif

__device__ __forceinline__ u16 f2bf(float x) {
  union { float f; unsigned u; } v;
  v.f = x;
  unsigned r = v.u + 0x7fffu + ((v.u >> 16) & 1u);
  return (u16)(r >> 16);
}

__device__ __forceinline__ float bf2f(u16 x) {
  union { unsigned u; float f; } v;
  v.u = ((unsigned)x) << 16;
  return v.f;
}

__device__ __forceinline__ u16 f2h(float x) {
  _Float16 h = (_Float16)x;
  return *(u16*)&h;
}

__device__ __forceinline__ unsigned pack2bf(float a, float b) {
  return (unsigned)f2bf(a) | ((unsigned)f2bf(b) << 16);
}

__device__ __forceinline__ float gelu_exact(float x) {
  return 0.5f * x * (1.0f + erff(x * 0.7071067811865475f));
}

__device__ __forceinline__ f32x4 mfma_16x16x32_bf16(u16x8 a, u16x8 b, f32x4 c) {
  asm("v_mfma_f32_16x16x32_bf16 %0, %1, %2, %0" : "+v"(c) : "v"(a), "v"(b));
  return c;
}

__device__ __forceinline__ float dot2h(h2 a, h2 b, float c) {
#ifdef HAVE_FDOT2
  return __builtin_amdgcn_fdot2(a, b, c, false);
#else
  return c + (float)a[0] * (float)b[0] + (float)a[1] * (float)b[1];
#endif
}

// Direct global->LDS DMA, 16B per lane.
__device__ __forceinline__ void gload_lds16(const u16* g, const u16* lds_base) {
  __builtin_amdgcn_global_load_lds(
      (const __attribute__((address_space(1))) unsigned int*)(uintptr_t)g,
      (__attribute__((address_space(3))) unsigned int*)(unsigned)(uintptr_t)lds_base,
      16, 0, 0);
}

__global__ __launch_bounds__(256) void split_kernel(const float* __restrict__ latents,
                                                    float* __restrict__ sp, float* __restrict__ gl) {
  int i = blockIdx.x * 256 + threadIdx.x;
  const int total = B * LT * D / 4;
  if (i >= total) return;
  float4 v = ((const float4*)latents)[i];
  int fi = i * 4;
  int d = fi % D;
  int row = fi / D;
  int l = row % LT;
  int b = row / LT;
  if (l < L) ((float4*)sp)[((size_t)(b * L + l) * D + d) / 4] = v;
  else ((float4*)gl)[((size_t)(b * G + (l - L)) * D + d) / 4] = v;
}

__global__ __launch_bounds__(256) void assemble_kernel(const float* __restrict__ sp,
                                                       const float* __restrict__ gl,
                                                       float* __restrict__ out) {
  int i = blockIdx.x * 256 + threadIdx.x;
  const int total = B * LT * D / 4;
  if (i >= total) return;
  int fi = i * 4;
  int d = fi % D;
  int row = fi / D;
  int l = row % LT;
  int b = row / LT;
  float4 v;
  if (l < L) v = ((const float4*)sp)[((size_t)(b * L + l) * D + d) / 4];
  else v = ((const float4*)gl)[((size_t)(b * G + (l - L)) * D + d) / 4];
  ((float4*)out)[i] = v;
}

// LayerNorm, bf16 output.
__global__ __launch_bounds__(256) void ln_kernel(const float* __restrict__ in,
                                                 const float* __restrict__ gw,
                                                 const float* __restrict__ bw,
                                                 u16* __restrict__ out) {
  int row = blockIdx.x;
  int t = threadIdx.x;
  const float* x = in + (size_t)row * D;
  float2 v = ((const float2*)x)[t];
  float s = v.x + v.y;
  float sq = v.x * v.x + v.y * v.y;
#pragma unroll
  for (int m = 1; m < 64; m <<= 1) {
    s += __shfl_xor(s, m, 64);
    sq += __shfl_xor(sq, m, 64);
  }
  __shared__ float ss[4], s2[4];
  int w = t >> 6;
  if ((t & 63) == 0) { ss[w] = s; s2[w] = sq; }
  __syncthreads();
  s = ss[0] + ss[1] + ss[2] + ss[3];
  sq = s2[0] + s2[1] + s2[2] + s2[3];
  float mean = s * (1.0f / D);
  float var = sq * (1.0f / D) - mean * mean;
  float rs = rsqrtf(var + 1e-5f);
  float2 gv = ((const float2*)gw)[t];
  float2 bv = ((const float2*)bw)[t];
  float ox = (v.x - mean) * rs * gv.x + bv.x;
  float oy = (v.y - mean) * rs * gv.y + bv.y;
  ((unsigned*)(out + (size_t)row * D))[t] = pack2bf(ox, oy);
}

// flat f32 -> bf16
__global__ __launch_bounds__(256) void cvt_bf16_kernel(const float* __restrict__ in,
                                                       u16* __restrict__ out, int n4) {
  int i = blockIdx.x * 256 + threadIdx.x;
  if (i >= n4) return;
  float4 v = ((const float4*)in)[i];
  ushort4 o;
  o.x = f2bf(v.x); o.y = f2bf(v.y); o.z = f2bf(v.z); o.w = f2bf(v.w);
  ((ushort4*)out)[i] = o;
}

// Transpose-convert weights: W fp32 [K][N] -> Wt bf16 [N][dstride] (cols 0..K-1 used).
struct WtJob { const float* src; u16* dst; int K; int N; int off; int dstride; };
struct WtJobs { WtJob j[16]; };

__global__ __launch_bounds__(256) void wt_convert_kernel(WtJobs jobs) {
  __shared__ float tile[32][33];
  int bid = blockIdx.x;
  int e = 0;
#pragma unroll
  for (int i = 1; i < 16; ++i) if (bid >= jobs.j[i].off) e = i;
  const WtJob& J = jobs.j[e];
  int ti = bid - J.off;
  int tiles_n = J.N >> 5;
  int tk = ti / tiles_n, tn = ti - tk * tiles_n;
  int t = threadIdx.x;
  int r = t >> 3, c4 = (t & 7) * 4;
  float4 v = *(const float4*)&J.src[(size_t)(tk * 32 + r) * J.N + tn * 32 + c4];
  tile[r][c4 + 0] = v.x; tile[r][c4 + 1] = v.y; tile[r][c4 + 2] = v.z; tile[r][c4 + 3] = v.w;
  __syncthreads();
  int r2 = t >> 3, k4 = (t & 7) * 4;
  ushort4 o;
  o.x = f2bf(tile[k4 + 0][r2]);
  o.y = f2bf(tile[k4 + 1][r2]);
  o.z = f2bf(tile[k4 + 2][r2]);
  o.w = f2bf(tile[k4 + 3][r2]);
  *(ushort4*)&J.dst[(size_t)(tn * 32 + r2) * J.dstride + tk * 32 + k4] = o;
}

// WQTt[(h*64+p)][c] = sum_d wkb[p][h*64+d] * wq[c][h*64+d]. grid (8h, 8ct).
__global__ __launch_bounds__(256) void comp_qt_kernel(const float* __restrict__ wq,
                                                      const float* __restrict__ wkb,
                                                      u16* __restrict__ out) {
  int h = blockIdx.x, ct = blockIdx.y;
  __shared__ float wk_s[64][68];
  __shared__ float wq_s[64][68];
  int t = threadIdx.x;
  int r = t >> 4, c4 = (t & 15) * 4;
#pragma unroll
  for (int i = 0; i < 4; ++i) {
    int rr = r + i * 16;
    *(float4*)&wk_s[rr][c4] = *(const float4*)&wkb[(size_t)rr * INNER + h * DH + c4];
    *(float4*)&wq_s[rr][c4] = *(const float4*)&wq[(size_t)(ct * 64 + rr) * INNER + h * DH + c4];
  }
  __syncthreads();
  int p = t >> 2, cb = (t & 3) * 16;
  float acc[16] = {};
  for (int d = 0; d < 64; ++d) {
    float a = wk_s[p][d];
#pragma unroll
    for (int j = 0; j < 16; ++j) acc[j] += a * wq_s[cb + j][d];
  }
  for (int j = 0; j < 16; ++j)
    out[(size_t)(h * 64 + p) * INNER + ct * 64 + cb + j] = f2bf(acc[j]);
}

// WO2t[j][512 + h*64 + p] = sum_d la_wo[h*64+d][j] * wvb[p][h*64+d]. grid (8h, 8jt).
__global__ __launch_bounds__(256) void comp_wo_kernel(const float* __restrict__ la_wo,
                                                      const float* __restrict__ wvb,
                                                      u16* __restrict__ WO2t) {
  int h = blockIdx.x, jt = blockIdx.y;
  __shared__ float lo_s[64][68];
  __shared__ float wv_s[64][68];
  int t = threadIdx.x;
  int r = t >> 4, c4 = (t & 15) * 4;
#pragma unroll
  for (int i = 0; i < 4; ++i) {
    int rr = r + i * 16;
    *(float4*)&lo_s[rr][c4] = *(const float4*)&la_wo[(size_t)(h * DH + rr) * D + jt * 64 + c4];
    *(float4*)&wv_s[rr][c4] = *(const float4*)&wvb[(size_t)rr * INNER + h * DH + c4];
  }
  __syncthreads();
  int j = t >> 2, pb = (t & 3) * 16;
  float acc[16] = {};
  for (int d = 0; d < 64; ++d) {
    float a = lo_s[d][j];
#pragma unroll
    for (int i = 0; i < 16; ++i) acc[i] += a * wv_s[pb + i][d];
  }
  for (int i = 0; i < 16; ++i)
    WO2t[(size_t)(jt * 64 + j) * 1024 + 512 + h * DH + pb + i] = f2bf(acc[i]);
}

// bf16 MFMA GEMM v3: ds_read(cur)->regs FIRST, then DMA-prefetch(next), then MFMA.
struct WSet { const u16* W[4]; void* out[4]; };

template <int BM, int BN>
__global__ __launch_bounds__(256) void gemm_v3_kernel(const u16* __restrict__ A, WSet gs,
                                                      const float* __restrict__ bias,
                                                      const float* __restrict__ res,
                                                      u16* __restrict__ out_bf,
                                                      int M, int K, int N, int act, unsigned obf) {
  constexpr int FM = BM / 32;
  constexpr int FN = BN / 32;
  __shared__ u16 As[2][BM * 64];
  __shared__ u16 Bs[2][BN * 64];
  int t = threadIdx.x;
  int wave = __builtin_amdgcn_readfirstlane(t >> 6);
  int lane = t & 63;
  int wr = wave >> 1, wc = wave & 1;
  int row16 = lane & 15, katom = lane >> 4;
  int bm = blockIdx.y * BM, bn = blockIdx.x * BN;
  const u16* W = gs.W[blockIdx.z];
  void* outp = gs.out[blockIdx.z];
  unsigned obz = (obf >> (blockIdx.z * 2)) & 3u;
  int srow = lane >> 3;
  int sg = lane & 7;
  int swz = row16 & 7;
  f32x4 acc[FM][FN] = {};

  auto stage = [&](int buf, int kb) {
#pragma unroll
    for (int c = 0; c < BM / 32; ++c) {
      int rowbase = wave * (BM / 4) + c * 8;
      int row = rowbase + srow;
      int gsrc = sg ^ (row & 7);
      gload_lds16(&A[(size_t)(bm + row) * K + kb + gsrc * 8], &As[buf][rowbase * 64]);
    }
#pragma unroll
    for (int c = 0; c < BN / 32; ++c) {
      int rowbase = wave * (BN / 4) + c * 8;
      int row = rowbase + srow;
      int gsrc = sg ^ (row & 7);
      gload_lds16(&W[(size_t)(bn + row) * K + kb + gsrc * 8], &Bs[buf][rowbase * 64]);
    }
  };

  stage(0, 0);
  __syncthreads();
  int nk = K >> 6;
  int cur = 0;
  for (int ti = 0; ti < nk; ++ti) {
    u16x8 af[2][FM], bf[2][FN];
#pragma unroll
    for (int kk = 0; kk < 2; ++kk) {
#pragma unroll
      for (int m = 0; m < FM; ++m) {
        int r = wr * (BM / 2) + m * 16 + row16;
        af[kk][m] = *(u16x8*)&As[cur][r * 64 + ((kk * 4 + katom) ^ swz) * 8];
      }
#pragma unroll
      for (int n = 0; n < FN; ++n) {
        int r = wc * (BN / 2) + n * 16 + row16;
        bf[kk][n] = *(u16x8*)&Bs[cur][r * 64 + ((kk * 4 + katom) ^ swz) * 8];
      }
    }
    __builtin_amdgcn_sched_barrier(0);
    if (ti + 1 < nk) stage(cur ^ 1, (ti + 1) << 6);
#pragma unroll
    for (int kk = 0; kk < 2; ++kk)
#pragma unroll
      for (int m = 0; m < FM; ++m)
#pragma unroll
        for (int n = 0; n < FN; ++n)
          acc[m][n] = mfma_16x16x32_bf16(af[kk][m], bf[kk][n], acc[m][n]);
    __syncthreads();
    cur ^= 1;
  }
#pragma unroll
  for (int m = 0; m < FM; ++m) {
    int row = bm + wr * (BM / 2) + m * 16 + katom * 4;
#pragma unroll
    for (int n = 0; n < FN; ++n) {
      int col = bn + wc * (BN / 2) + n * 16 + row16;
      float bsv = bias ? bias[col] : 0.f;
#pragma unroll
      for (int r = 0; r < 4; ++r) {
        float v = acc[m][n][r] + bsv;
        if (act) v = gelu_exact(v);
        size_t oi = (size_t)(row + r) * N + col;
        if (res) v += res[oi];
        if (obz == 1) ((u16*)outp)[oi] = f2bf(v);
        else if (obz == 3) ((u16*)outp)[oi] = f2h(v);
        else {
          ((float*)outp)[oi] = v;
          if (obz == 2) out_bf[oi] = f2bf(v);
        }
      }
    }
  }
}

// Local KNN attention v3: Q,TQ bf16; K,V fp16. Writes OA = [o_gather | ar] bf16.
__global__ __launch_bounds__(256) void local_attn2_kernel(
    const u16* __restrict__ Qh, const u16* __restrict__ Kh, const u16* __restrict__ Vh,
    const u16* __restrict__ TQh, const float* __restrict__ rpe, const float* __restrict__ dist,
    const int* __restrict__ idx, const float* __restrict__ lsig, u16* __restrict__ OA) {
  int blk = blockIdx.x;
  int b = blk >> 11;
  int t = threadIdx.x;
  __shared__ _Float16 q_s[INNER];
  __shared__ float tq_s[INNER];
  __shared__ float rpe_s[KN][68];
  __shared__ float a_s[H][KN + 1];
  __shared__ float ar_s[H][PE + 2];
  __shared__ int idx_s[KN];
  __shared__ float dist_s[KN];
  __shared__ float sig_s[H];
  size_t row = (size_t)blk;
  {
    unsigned qp = ((const unsigned*)(Qh + row * INNER))[t];
    q_s[2 * t] = (_Float16)bf2f((u16)qp);
    q_s[2 * t + 1] = (_Float16)bf2f((u16)(qp >> 16));
    unsigned tp = ((const unsigned*)(TQh + row * INNER))[t];
    tq_s[2 * t] = bf2f((u16)tp);
    tq_s[2 * t + 1] = bf2f((u16)(tp >> 16));
  }
  {
    const float* rp = rpe + row * (KN * PE);
    int k = t >> 3, p0 = (t & 7) * 8;
    *(float4*)&rpe_s[k][p0] = *(const float4*)&rp[k * PE + p0];
    *(float4*)&rpe_s[k][p0 + 4] = *(const float4*)&rp[k * PE + p0 + 4];
  }
  if (t < KN) {
    idx_s[t] = idx[row * KN + t];
    dist_s[t] = dist[row * KN + t];
  }
  if (t < H) sig_s[t] = expf(2.0f * lsig[t]);
  __syncthreads();
  {
    int h = t >> 5, k = t & 31;
    int rr = idx_s[k];
    const u16* krow = Kh + ((size_t)(b * L + rr)) * INNER + h * DH;
    float acc = 0.f;
#pragma unroll
    for (int i = 0; i < 8; ++i) {
      u16x8 kv = *(const u16x8*)&krow[i * 8];
      u16x8 qv = *(const u16x8*)&q_s[h * DH + i * 8];
      const h2* kk = (const h2*)&kv;
      const h2* qq = (const h2*)&qv;
      acc = dot2h(kk[0], qq[0], acc);
      acc = dot2h(kk[1], qq[1], acc);
      acc = dot2h(kk[2], qq[2], acc);
      acc = dot2h(kk[3], qq[3], acc);
    }
    float accr = 0.f;
    const float* tqh = tq_s + h * DH;
#pragma unroll
    for (int p = 0; p < PE; p += 4) {
      float4 r4 = *(float4*)&rpe_s[k][p];
      float4 t4 = *(const float4*)&tqh[p];
      accr += r4.x * t4.x + r4.y * t4.y + r4.z * t4.z + r4.w * t4.w;
    }
    float dd = dist_s[k];
    float logit = SCALE * (acc + accr) - dd * dd / (2.0f * sig_s[h]);
    float mx = logit;
#pragma unroll
    for (int m = 1; m < 32; m <<= 1) mx = fmaxf(mx, __shfl_xor(mx, m, 64));
    float e = expf(logit - mx);
    float sum = e;
#pragma unroll
    for (int m = 1; m < 32; m <<= 1) sum += __shfl_xor(sum, m, 64);
    a_s[h][k] = e / sum;
  }
  __syncthreads();
  {
    int hh = t >> 6, p = t & 63;
    float acc0 = 0.f, acc1 = 0.f;
#pragma unroll
    for (int k = 0; k < KN; ++k) {
      float rv = rpe_s[k][p];
      acc0 += a_s[hh][k] * rv;
      acc1 += a_s[hh + 4][k] * rv;
    }
    ar_s[hh][p] = acc0;
    ar_s[hh + 4][p] = acc1;
  }
  __syncthreads();
  {
    int h0 = t >> 5;
    h2 o2;
    o2[0] = (_Float16)0.f;
    o2[1] = (_Float16)0.f;
#pragma unroll 8
    for (int k = 0; k < KN; ++k) {
      unsigned vv = *(const unsigned*)&Vh[((size_t)(b * L + idx_s[k])) * INNER + 2 * t];
      h2 v2 = *(h2*)&vv;
      _Float16 ah = (_Float16)a_s[h0][k];
      h2 a2;
      a2[0] = ah; a2[1] = ah;
      o2 = a2 * v2 + o2;
    }
    ((unsigned*)&OA[row * 1024])[t] = pack2bf((float)o2[0], (float)o2[1]);
    int p0 = 2 * (t & 31);
    ((unsigned*)&OA[row * 1024 + 512])[t] = pack2bf(ar_s[t >> 5][p0], ar_s[t >> 5][p0 + 1]);
  }
}

// spatial->global cross attention, MFMA version.
// Block = (64-query tile, h, b). All bf16 inputs. Output bf16.
__global__ __launch_bounds__(256) void s2g_attn_mfma_kernel(const u16* __restrict__ Qh,
                                                            const u16* __restrict__ Kg,
                                                            const u16* __restrict__ Vg,
                                                            u16* __restrict__ O) {
  int l0 = blockIdx.x * 64;
  int h = blockIdx.y;
  int b = blockIdx.z;
  int t = threadIdx.x;
  int wave = __builtin_amdgcn_readfirstlane(t >> 6);
  int lane = t & 63;
  int wr = wave >> 1, wc = wave & 1;
  int row16 = lane & 15, katom = lane >> 4;
  __shared__ u16 Qs[64 * 72];
  __shared__ u16 Ks[128 * 72];     // reused for VT [64][136] after logits
  __shared__ u16 Ps[64 * 136];
  __shared__ float redm[2][64], reds[2][64];
  u16* VT = Ks;

  for (int i = t; i < 512; i += 256) {
    int r = i >> 3, s = i & 7;
    *(u16x8*)&Qs[r * 72 + s * 8] = *(const u16x8*)&Qh[((size_t)(b * L + l0 + r)) * INNER + h * DH + s * 8];
  }
  for (int i = t; i < 1024; i += 256) {
    int r = i >> 3, s = i & 7;
    *(u16x8*)&Ks[r * 72 + s * 8] = *(const u16x8*)&Kg[((size_t)(b * G + r)) * INNER + h * DH + s * 8];
  }
  __syncthreads();

  // logits: acc[m][n], q = wr*32+m*16+katom*4+r, key = wc*64+n*16+row16
  f32x4 acc[2][4] = {};
#pragma unroll
  for (int kk = 0; kk < 2; ++kk) {
    u16x8 af[2], bf[4];
#pragma unroll
    for (int m = 0; m < 2; ++m)
      af[m] = *(u16x8*)&Qs[(wr * 32 + m * 16 + row16) * 72 + kk * 32 + katom * 8];
#pragma unroll
    for (int n = 0; n < 4; ++n)
      bf[n] = *(u16x8*)&Ks[(wc * 64 + n * 16 + row16) * 72 + kk * 32 + katom * 8];
#pragma unroll
    for (int m = 0; m < 2; ++m)
#pragma unroll
      for (int n = 0; n < 4; ++n) acc[m][n] = mfma_16x16x32_bf16(af[m], bf[n], acc[m][n]);
  }
#pragma unroll
  for (int m = 0; m < 2; ++m)
#pragma unroll
    for (int n = 0; n < 4; ++n)
#pragma unroll
      for (int r = 0; r < 4; ++r) acc[m][n][r] *= SCALE;

  // per-(m,r) row max over n and 16 lanes
  float mx[2][4];
#pragma unroll
  for (int m = 0; m < 2; ++m)
#pragma unroll
    for (int r = 0; r < 4; ++r) {
      float v = fmaxf(fmaxf(acc[m][0][r], acc[m][1][r]), fmaxf(acc[m][2][r], acc[m][3][r]));
#pragma unroll
      for (int msk = 1; msk < 16; msk <<= 1) v = fmaxf(v, __shfl_xor(v, msk, 64));
      mx[m][r] = v;
    }
  if (row16 == 0) {
#pragma unroll
    for (int m = 0; m < 2; ++m)
#pragma unroll
      for (int r = 0; r < 4; ++r) redm[wc][wr * 32 + m * 16 + katom * 4 + r] = mx[m][r];
  }
  __syncthreads();  // redm ready; Ks logits reads done -> VT overlay allowed

  // V load transposed into VT[d][m] (stride 136), overlapping softmax work
  {
    int m = t >> 1, ch = t & 1;
    const u16* vrow = Vg + ((size_t)(b * G + m)) * INNER + h * DH + ch * 32;
#pragma unroll
    for (int j = 0; j < 8; ++j) {
      ushort4 v = *(const ushort4*)&vrow[j * 4];
      int c = ch * 32 + j * 4;
      VT[(c + 0) * 136 + m] = v.x;
      VT[(c + 1) * 136 + m] = v.y;
      VT[(c + 2) * 136 + m] = v.z;
      VT[(c + 3) * 136 + m] = v.w;
    }
  }

  // exp + row sum
  float sm[2][4];
#pragma unroll
  for (int m = 0; m < 2; ++m)
#pragma unroll
    for (int r = 0; r < 4; ++r) {
      int qi = wr * 32 + m * 16 + katom * 4 + r;
      float gm = fmaxf(redm[0][qi], redm[1][qi]);
      float s = 0.f;
#pragma unroll
      for (int n = 0; n < 4; ++n) {
        float e = expf(acc[m][n][r] - gm);
        acc[m][n][r] = e;
        s += e;
      }
#pragma unroll
      for (int msk = 1; msk < 16; msk <<= 1) s += __shfl_xor(s, msk, 64);
      sm[m][r] = s;
    }
  if (row16 == 0) {
#pragma unroll
    for (int m = 0; m < 2; ++m)
#pragma unroll
      for (int r = 0; r < 4; ++r) reds[wc][wr * 32 + m * 16 + katom * 4 + r] = sm[m][r];
  }
  __syncthreads();  // reds + VT ready

  // normalize, write P bf16
#pragma unroll
  for (int m = 0; m < 2; ++m)
#pragma unroll
    for (int r = 0; r < 4; ++r) {
      int qi = wr * 32 + m * 16 + katom * 4 + r;
      float inv = 1.0f / (reds[0][qi] + reds[1][qi]);
#pragma unroll
      for (int n = 0; n < 4; ++n)
        Ps[qi * 136 + wc * 64 + n * 16 + row16] = f2bf(acc[m][n][r] * inv);
    }
  __syncthreads();  // Ps ready

  // PV: out[q][d] = sum_m P[q][m] * VT[d][m]; q tile wr*32, d tile wc*32
  f32x4 oacc[2][2] = {};
#pragma unroll
  for (int kk = 0; kk < 4; ++kk) {
    u16x8 pa[2], vb[2];
#pragma unroll
    for (int m = 0; m < 2; ++m)
      pa[m] = *(u16x8*)&Ps[(wr * 32 + m * 16 + row16) * 136 + kk * 32 + katom * 8];
#pragma unroll
    for (int n = 0; n < 2; ++n)
      vb[n] = *(u16x8*)&VT[(wc * 32 + n * 16 + row16) * 136 + kk * 32 + katom * 8];
#pragma unroll
    for (int m = 0; m < 2; ++m)
#pragma unroll
      for (int n = 0; n < 2; ++n) oacc[m][n] = mfma_16x16x32_bf16(pa[m], vb[n], oacc[m][n]);
  }
#pragma unroll
  for (int m = 0; m < 2; ++m) {
    int q = wr * 32 + m * 16 + katom * 4;
#pragma unroll
    for (int n = 0; n < 2; ++n) {
      int d = wc * 32 + n * 16 + row16;
#pragma unroll
      for (int r = 0; r < 4; ++r)
        O[((size_t)(b * L + l0 + q + r)) * INNER + h * DH + d] = f2bf(oacc[m][n][r]);
    }
  }
}

// ---------------- g2s: 5-phase MFMA pipeline ----------------
__global__ __launch_bounds__(256) void g2s_logits_kernel(const u16* __restrict__ QGh,
                                                         const u16* __restrict__ KBh,
                                                         float* __restrict__ LG) {
  __shared__ u16 Qs[128 * 72];
  __shared__ u16 Ks[128 * 72];
  int nt = blockIdx.x, h = blockIdx.y, b = blockIdx.z;
  int t = threadIdx.x;
  int wave = t >> 6, lane = t & 63;
  int row16 = lane & 15, katom = lane >> 4;
#pragma unroll
  for (int i = 0; i < 4; ++i) {
    int row = (t >> 3) + i * 32;
    int cg = t & 7;
    *(u16x8*)&Qs[row * 72 + cg * 8] =
        *(const u16x8*)&QGh[((size_t)(b * G + row)) * INNER + h * DH + cg * 8];
    *(u16x8*)&Ks[row * 72 + cg * 8] =
        *(const u16x8*)&KBh[((size_t)(b * L + nt * 128 + row)) * INNER + h * DH + cg * 8];
  }
  __syncthreads();
  f32x4 acc[2][8] = {};
#pragma unroll
  for (int kk = 0; kk < 2; ++kk) {
    u16x8 af[2], bf[8];
#pragma unroll
    for (int qt = 0; qt < 2; ++qt)
      af[qt] = *(u16x8*)&Qs[(wave * 32 + qt * 16 + row16) * 72 + kk * 32 + katom * 8];
#pragma unroll
    for (int nm = 0; nm < 8; ++nm)
      bf[nm] = *(u16x8*)&Ks[(nm * 16 + row16) * 72 + kk * 32 + katom * 8];
#pragma unroll
    for (int qt = 0; qt < 2; ++qt)
#pragma unroll
      for (int nm = 0; nm < 8; ++nm) acc[qt][nm] = mfma_16x16x32_bf16(af[qt], bf[nm], acc[qt][nm]);
  }
#pragma unroll
  for (int qt = 0; qt < 2; ++qt) {
    int g = wave * 32 + qt * 16 + katom * 4;
#pragma unroll
    for (int nm = 0; nm < 8; ++nm) {
      int m = nt * 128 + nm * 16 + row16;
#pragma unroll
      for (int r = 0; r < 4; ++r)
        LG[(((size_t)(b * H + h) * G) + g + r) * L + m] = acc[qt][nm][r] * SCALE;
    }
  }
}

__global__ __launch_bounds__(256) void g2s_softmax_kernel(const float* __restrict__ LG,
                                                          u16* __restrict__ WG) {
  int g = blockIdx.x & (G - 1);
  int b = blockIdx.x >> 7;
  int t = threadIdx.x;
  int w = t >> 6, lane = t & 63;
  __shared__ float red[8];
  for (int h = 0; h < H; ++h) {
    size_t base = (((size_t)(b * H + h) * G) + g) * L;
    float4 lo = *(const float4*)&LG[base + t * 8];
    float4 hi = *(const float4*)&LG[base + t * 8 + 4];
    float mx = fmaxf(fmaxf(fmaxf(lo.x, lo.y), fmaxf(lo.z, lo.w)),
                     fmaxf(fmaxf(hi.x, hi.y), fmaxf(hi.z, hi.w)));
#pragma unroll
    for (int m = 1; m < 64; m <<= 1) mx = fmaxf(mx, __shfl_xor(mx, m, 64));
    if (lane == 0) red[w] = mx;
    __syncthreads();
    mx = fmaxf(fmaxf(red[0], red[1]), fmaxf(red[2], red[3]));
    float e[8];
    e[0] = expf(lo.x - mx); e[1] = expf(lo.y - mx); e[2] = expf(lo.z - mx); e[3] = expf(lo.w - mx);
    e[4] = expf(hi.x - mx); e[5] = expf(hi.y - mx); e[6] = expf(hi.z - mx); e[7] = expf(hi.w - mx);
    float sum = e[0] + e[1] + e[2] + e[3] + e[4] + e[5] + e[6] + e[7];
#pragma unroll
    for (int m = 1; m < 64; m <<= 1) sum += __shfl_xor(sum, m, 64);
    if (lane == 0) red[4 + w] = sum;
    __syncthreads();
    float inv = 1.0f / (red[4] + red[5] + red[6] + red[7]);
    ushort4 o0, o1;
    o0.x = f2bf(e[0] * inv); o0.y = f2bf(e[1] * inv); o0.z = f2bf(e[2] * inv); o0.w = f2bf(e[3] * inv);
    o1.x = f2bf(e[4] * inv); o1.y = f2bf(e[5] * inv); o1.z = f2bf(e[6] * inv); o1.w = f2bf(e[7] * inv);
    *(ushort4*)&WG[base + t * 8] = o0;
    *(ushort4*)&WG[base + t * 8 + 4] = o1;
    __syncthreads();
  }
}

__global__ __launch_bounds__(256) void g2s_vt_kernel(const u16* __restrict__ VBh,
                                                     u16* __restrict__ Vt) {
  __shared__ u16 tile[32][36];
  int mt = blockIdx.x, ct = blockIdx.y, b = blockIdx.z;
  int t = threadIdx.x;
  int r = t >> 3, c4 = (t & 7) * 4;
  *(ushort4*)&tile[r][c4] =
      *(const ushort4*)&VBh[((size_t)(b * L + mt * 32 + r)) * INNER + ct * 32 + c4];
  __syncthreads();
  int r2 = t >> 3, m4 = (t & 7) * 4;
  int c = ct * 32 + r2;
  int h = c >> 6, d = c & 63;
  ushort4 o;
  o.x = tile[m4 + 0][r2]; o.y = tile[m4 + 1][r2]; o.z = tile[m4 + 2][r2]; o.w = tile[m4 + 3][r2];
  *(ushort4*)&Vt[(((size_t)(b * H + h) * DH) + d) * L + mt * 32 + m4] = o;
}

__global__ __launch_bounds__(256) void g2s_pv_kernel(const u16* __restrict__ WG,
                                                     const u16* __restrict__ Vt,
                                                     float* __restrict__ Opart) {
  __shared__ u16 Ws[128 * 40];
  __shared__ u16 Vs[64 * 40];
  int s = blockIdx.x, h = blockIdx.y, b = blockIdx.z;
  int t = threadIdx.x;
  int wave = t >> 6, lane = t & 63;
  int row16 = lane & 15, katom = lane >> 4;
  int r0 = t >> 2, cg = t & 3;
  size_t wbase = ((size_t)(b * H + h) * G) * L;
  size_t vbase = ((size_t)(b * H + h) * DH) * L;
  f32x4 acc[2][4] = {};
  for (int it = 0; it < 8; ++it) {
    int m0 = s * 256 + it * 32;
    u16x8 w0 = *(const u16x8*)&WG[wbase + (size_t)r0 * L + m0 + cg * 8];
    u16x8 w1 = *(const u16x8*)&WG[wbase + (size_t)(r0 + 64) * L + m0 + cg * 8];
    u16x8 v0 = *(const u16x8*)&Vt[vbase + (size_t)(t >> 2) * L + m0 + cg * 8];
    __syncthreads();
    *(u16x8*)&Ws[r0 * 40 + cg * 8] = w0;
    *(u16x8*)&Ws[(r0 + 64) * 40 + cg * 8] = w1;
    *(u16x8*)&Vs[(t >> 2) * 40 + cg * 8] = v0;
    __syncthreads();
    u16x8 af[2], bf[4];
#pragma unroll
    for (int qt = 0; qt < 2; ++qt)
      af[qt] = *(u16x8*)&Ws[(wave * 32 + qt * 16 + row16) * 40 + katom * 8];
#pragma unroll
    for (int nd = 0; nd < 4; ++nd)
      bf[nd] = *(u16x8*)&Vs[(nd * 16 + row16) * 40 + katom * 8];
#pragma unroll
    for (int qt = 0; qt < 2; ++qt)
#pragma unroll
      for (int nd = 0; nd < 4; ++nd) acc[qt][nd] = mfma_16x16x32_bf16(af[qt], bf[nd], acc[qt][nd]);
  }
  size_t obase = (((size_t)(b * H + h) * 8) + s) * G * DH;
#pragma unroll
  for (int qt = 0; qt < 2; ++qt) {
    int g = wave * 32 + qt * 16 + katom * 4;
#pragma unroll
    for (int nd = 0; nd < 4; ++nd) {
      int d = nd * 16 + row16;
#pragma unroll
      for (int r = 0; r < 4; ++r) Opart[obase + (size_t)(g + r) * DH + d] = acc[qt][nd][r];
    }
  }
}

__global__ __launch_bounds__(256) void g2s_combine_kernel(const float* __restrict__ Opart,
                                                          u16* __restrict__ OGh) {
  int g = blockIdx.x & (G - 1);
  int b = blockIdx.x >> 7;
  int t = threadIdx.x;
  int h = t >> 5, d0 = (t & 31) * 2;
  float o0 = 0.f, o1 = 0.f;
#pragma unroll
  for (int s = 0; s < 8; ++s) {
    const float* p = Opart + ((((size_t)(b * H + h) * 8) + s) * G + g) * DH + d0;
    o0 += p[0];
    o1 += p[1];
  }
  *(unsigned*)&OGh[((size_t)(b * G + g)) * INNER + h * DH + d0] = pack2bf(o0, o1);
}

}  // namespace

extern "C" void kernel_launch(void* const* d_in, const int* in_sizes, int n_in,
                              void* d_out, int out_size, void* d_ws, size_t ws_size,
                              hipStream_t stream) {
  (void)in_sizes; (void)n_in; (void)out_size; (void)ws_size;
  const float* latents = (const float*)d_in[0];
  const float* rpe = (const float*)d_in[1];
  const float* dist = (const float*)d_in[2];
  const float* sn_g = (const float*)d_in[3];
  const float* sn_b = (const float*)d_in[4];
  const float* la_wq = (const float*)d_in[5];
  const float* la_wk = (const float*)d_in[6];
  const float* la_wv = (const float*)d_in[7];
  const float* la_wo = (const float*)d_in[8];
  const float* la_bo = (const float*)d_in[9];
  const float* log_sigma = (const float*)d_in[10];
  const float* scn_g = (const float*)d_in[11];
  const float* scn_b = (const float*)d_in[12];
  const float* s2g_wq = (const float*)d_in[13];
  const float* s2g_wk = (const float*)d_in[14];
  const float* s2g_wv = (const float*)d_in[15];
  const float* s2g_wo = (const float*)d_in[16];
  const float* s2g_bo = (const float*)d_in[17];
  const float* gcn_g = (const float*)d_in[18];
  const float* gcn_b = (const float*)d_in[19];
  const float* g2s_wq = (const float*)d_in[20];
  const float* g2s_wk = (const float*)d_in[21];
  const float* g2s_wv = (const float*)d_in[22];
  const float* g2s_wo = (const float*)d_in[23];
  const float* g2s_bo = (const float*)d_in[24];
  const float* gfn_g = (const float*)d_in[25];
  const float* gfn_b = (const float*)d_in[26];
  const float* gff_w1 = (const float*)d_in[27];
  const float* gff_b1 = (const float*)d_in[28];
  const float* gff_w2 = (const float*)d_in[29];
  const float* gff_b2 = (const float*)d_in[30];
  const float* sfn_g = (const float*)d_in[31];
  const float* sfn_b = (const float*)d_in[32];
  const float* sff_w1 = (const float*)d_in[33];
  const float* sff_b1 = (const float*)d_in[34];
  const float* sff_w2 = (const float*)d_in[35];
  const float* sff_b2 = (const float*)d_in[36];
  const int* topk = (const int*)d_in[37];
  const float* wkb = la_wk + (size_t)D * INNER;
  const float* wvb = la_wv + (size_t)D * INNER;

  // ---- workspace layout ----
  char* wsb = (char*)d_ws;
  size_t off = 0;
  auto alloc = [&](size_t bytes) {
    char* p = wsb + off;
    off += (bytes + 255) & ~(size_t)255;
    return p;
  };
  const size_t SPn = (size_t)B * L * D;
  const size_t GLn = (size_t)B * G * D;
  float* SP = (float*)alloc(SPn * 4);
  float* GL = (float*)alloc(GLn * 4);
  float* QB = (float*)alloc(SPn * 4);
  float* KB = (float*)alloc(SPn * 4);
  float* VB = (float*)alloc(SPn * 4);
  float* S1 = (float*)alloc(SPn * 4);
  float* S2 = (float*)alloc(SPn * 4);
  float* G1 = (float*)alloc(GLn * 4);
  float* G2 = (float*)alloc(GLn * 4);
  float* QG = (float*)alloc(GLn * 4);
  float* KG = (float*)alloc(GLn * 4);
  float* VG = (float*)alloc(GLn * 4);
  u16* XNh = (u16*)alloc(SPn * 2);
  u16* OBh = (u16*)alloc(SPn * 2);
  u16* S2h = (u16*)alloc(SPn * 2);
  u16* HSh = (u16*)alloc((size_t)B * L * FF * 2);
  u16* GLh = (u16*)alloc(GLn * 2);
  u16* GNh = (u16*)alloc(GLn * 2);
  u16* OGh = (u16*)alloc(GLn * 2);
  u16* HGh = (u16*)alloc((size_t)B * G * FF * 2);
  const size_t SQ = 512 * 512, BIG = 512 * 2048;
  u16* WT = (u16*)alloc((12 * SQ + 4 * BIG) * 2);
  u16* la_wq_t = WT + 0 * SQ;
  u16* la_wk_t = WT + 1 * SQ;
  u16* la_wv_t = WT + 2 * SQ;
  u16* s2g_wq_t = WT + 4 * SQ;
  u16* s2g_wk_t = WT + 5 * SQ;
  u16* s2g_wv_t = WT + 6 * SQ;
  u16* s2g_wo_t = WT + 7 * SQ;
  u16* g2s_wq_t = WT + 8 * SQ;
  u16* g2s_wk_t = WT + 9 * SQ;
  u16* g2s_wv_t = WT + 10 * SQ;
  u16* g2s_wo_t = WT + 11 * SQ;
  u16* gff1_t = WT + 12 * SQ;
  u16* gff2_t = WT + 12 * SQ + BIG;
  u16* sff1_t = WT + 12 * SQ + 2 * BIG;
  u16* sff2_t = WT + 12 * SQ + 3 * BIG;
  u16* WQTt = (u16*)alloc(SQ * 2);
  u16* WO2t = (u16*)alloc(512 * 1024 * 2);

  // local-path bf16/fp16 aliases
  u16* lkh = (u16*)KB;
  u16* lvh = (u16*)KB + SPn;
  u16* ltqh = (u16*)VB;
  u16* lqh = (u16*)VB + SPn;
  u16* OA = (u16*)QB;

  // s2g aliases
  u16* QBh = (u16*)QB;       // bf16 Q for s2g (QB dead after local OA gemm)
  u16* KGh = (u16*)KG;
  u16* VGh = (u16*)VG;

  // g2s aliases over dead regions (stream-sequential => safe)
  float* LG = KB;
  u16* WG = (u16*)S1;
  u16* KBh = (u16*)QB;
  u16* VBh = (u16*)QB + SPn;
  u16* QGh = HSh;
  u16* Vt = HSh + GLn;
  float* Opart = (float*)(HSh + GLn + (size_t)B * H * DH * L);

  const int threads = 256;
  int nsplit = (B * LT * D / 4 + 255) / 256;

  split_kernel<<<nsplit, threads, 0, stream>>>(latents, SP, GL);

  // ---- weight transpose-convert + composite weights ----
  {
    WtJobs jobs;
    auto set = [&](int i, const float* s, u16* d, int K, int N, int offv, int dstride) {
      jobs.j[i].src = s; jobs.j[i].dst = d; jobs.j[i].K = K; jobs.j[i].N = N;
      jobs.j[i].off = offv; jobs.j[i].dstride = dstride;
    };
    int o = 0;
    set(0, la_wq, la_wq_t, 512, 512, o, 512); o += 256;
    set(1, la_wk, la_wk_t, 512, 512, o, 512); o += 256;
    set(2, la_wv, la_wv_t, 512, 512, o, 512); o += 256;
    set(3, la_wo, WO2t, 512, 512, o, 1024); o += 256;
    set(4, s2g_wq, s2g_wq_t, 512, 512, o, 512); o += 256;
    set(5, s2g_wk, s2g_wk_t, 512, 512, o, 512); o += 256;
    set(6, s2g_wv, s2g_wv_t, 512, 512, o, 512); o += 256;
    set(7, s2g_wo, s2g_wo_t, 512, 512, o, 512); o += 256;
    set(8, g2s_wq, g2s_wq_t, 512, 512, o, 512); o += 256;
    set(9, g2s_wk, g2s_wk_t, 512, 512, o, 512); o += 256;
    set(10, g2s_wv, g2s_wv_t, 512, 512, o, 512); o += 256;
    set(11, g2s_wo, g2s_wo_t, 512, 512, o, 512); o += 256;
    set(12, gff_w1, gff1_t, 512, 2048, o, 512); o += 1024;
    set(13, gff_w2, gff2_t, 2048, 512, o, 2048); o += 1024;
    set(14, sff_w1, sff1_t, 512, 2048, o, 512); o += 1024;
    set(15, sff_w2, sff2_t, 2048, 512, o, 2048); o += 1024;
    wt_convert_kernel<<<o, threads, 0, stream>>>(jobs);
  }
  comp_qt_kernel<<<dim3(8, 8), threads, 0, stream>>>(la_wq, wkb, WQTt);
  comp_wo_kernel<<<dim3(8, 8), threads, 0, stream>>>(la_wo, wvb, WO2t);

  auto gemm = [&](const u16* A, const u16* Wt, const float* bias, const float* res,
                  void* out, int M, int K, int N, int act, unsigned obf, u16* out_bf) {
    WSet gs{};
    gs.W[0] = Wt; gs.out[0] = out;
    if (N >= 1024)
      gemm_v3_kernel<64, 128><<<dim3(N / 128, M / 64, 1), threads, 0, stream>>>(
          A, gs, bias, res, out_bf, M, K, N, act, obf);
    else
      gemm_v3_kernel<64, 64><<<dim3(N / 64, M / 64, 1), threads, 0, stream>>>(
          A, gs, bias, res, out_bf, M, K, N, act, obf);
  };
  auto gemm_multi = [&](const u16* A, const u16* W0, const u16* W1, const u16* W2, const u16* W3,
                        void* o0, void* o1, void* o2, void* o3, int nw, int M, int K, int N,
                        unsigned obf) {
    WSet gs{};
    gs.W[0] = W0; gs.W[1] = W1; gs.W[2] = W2; gs.W[3] = W3;
    gs.out[0] = o0; gs.out[1] = o1; gs.out[2] = o2; gs.out[3] = o3;
    gemm_v3_kernel<64, 64><<<dim3(N / 64, M / 64, nw), threads, 0, stream>>>(
        A, gs, nullptr, nullptr, nullptr, M, K, N, 0, obf);
  };

  // --- local KNN attention block ---
  ln_kernel<<<B * L, threads, 0, stream>>>(SP, sn_g, sn_b, XNh);
  // obf per z: Q bf16(1), K fp16(3), V fp16(3), TQ bf16(1)
  gemm_multi(XNh, la_wq_t, la_wk_t, la_wv_t, WQTt, lqh, lkh, lvh, ltqh, 4, B * L, D, INNER,
             1u | (3u << 2) | (3u << 4) | (1u << 6));
  local_attn2_kernel<<<B * L, threads, 0, stream>>>(lqh, lkh, lvh, ltqh, rpe, dist, topk,
                                                    log_sigma, OA);
  gemm(OA, WO2t, la_bo, SP, S1, B * L, 1024, D, 0, 0, nullptr);

  // --- spatial -> global cross attention (MFMA) ---
  ln_kernel<<<B * L, threads, 0, stream>>>(S1, scn_g, scn_b, XNh);
  gemm(XNh, s2g_wq_t, nullptr, nullptr, QBh, B * L, D, INNER, 0, 1, nullptr);
  cvt_bf16_kernel<<<(int)(GLn / 4 + 255) / 256, threads, 0, stream>>>(GL, GLh, (int)(GLn / 4));
  gemm_multi(GLh, s2g_wk_t, s2g_wv_t, nullptr, nullptr, KGh, VGh, nullptr, nullptr, 2, B * G, D, INNER,
             1u | (1u << 2));
  s2g_attn_mfma_kernel<<<dim3(L / 64, H, B), threads, 0, stream>>>(QBh, KGh, VGh, OBh);
  gemm(OBh, s2g_wo_t, s2g_bo, S1, S2, B * L, INNER, D, 0, 2, S2h);  // dual write f32+bf16

  // --- global -> spatial cross attention (ctx = updated spatial S2) ---
  ln_kernel<<<B * G, threads, 0, stream>>>(GL, gcn_g, gcn_b, GNh);
  gemm(GNh, g2s_wq_t, nullptr, nullptr, QGh, B * G, D, INNER, 0, 1, nullptr);
  gemm_multi(S2h, g2s_wk_t, g2s_wv_t, nullptr, nullptr, KBh, VBh, nullptr, nullptr, 2, B * L, D, INNER,
             1u | (1u << 2));
  g2s_vt_kernel<<<dim3(L / 32, INNER / 32, B), threads, 0, stream>>>(VBh, Vt);
  g2s_logits_kernel<<<dim3(L / 128, H, B), threads, 0, stream>>>(QGh, KBh, LG);
  g2s_softmax_kernel<<<B * G, threads, 0, stream>>>(LG, WG);
  g2s_pv_kernel<<<dim3(8, H, B), threads, 0, stream>>>(WG, Vt, Opart);
  g2s_combine_kernel<<<B * G, threads, 0, stream>>>(Opart, OGh);
  gemm(OGh, g2s_wo_t, g2s_bo, GL, G1, B * G, INNER, D, 0, 0, nullptr);

  // --- global FFN ---
  ln_kernel<<<B * G, threads, 0, stream>>>(G1, gfn_g, gfn_b, GNh);
  gemm(GNh, gff1_t, gff_b1, nullptr, HGh, B * G, D, FF, 1, 1, nullptr);
  gemm(HGh, gff2_t, gff_b2, G1, G2, B * G, FF, D, 0, 0, nullptr);

  // --- spatial FFN ---
  ln_kernel<<<B * L, threads, 0, stream>>>(S2, sfn_g, sfn_b, XNh);
  gemm(XNh, sff1_t, sff_b1, nullptr, HSh, B * L, D, FF, 1, 1, nullptr);
  gemm(HSh, sff2_t, sff_b2, S2, S1, B * L, FF, D, 0, 0, nullptr);

  assemble_kernel<<<nsplit, threads, 0, stream>>>(S1, G2, (float*)d_out);
}

// Round 10
// 319.135 us; speedup vs baseline: 1.3868x; 1.0103x over previous
//
#include <hip/hip_runtime.h>
#include <math.h>

namespace {
constexpr int D = 512;
constexpr int PE = 64;
constexpr int H = 8;
constexpr int DH = 64;
constexpr int INNER = 512;
constexpr int FF = 2048;
constexpr int B = 2;
constexpr int L = 2048;
constexpr int KN = 32;
constexpr int G = 128;
constexpr int LT = L + G;
constexpr float SCALE = 0.125f;

typedef unsigned short u16;
typedef unsigned short u16x8 __attribute__((ext_vector_type(8)));
typedef float f32x4 __attribute__((ext_vector_type(4)));
typedef _Float16 h2 __attribute__((ext_vector_type(2)));

#if defined(__has_builtin)
#if __has_builtin(__builtin_amdgcn_fdot2)
#define HAVE_FDOT2 1
#endif
#endif

__device__ __forceinline__ u16 f2bf(float x) {
  union { float f; unsigned u; } v;
  v.f = x;
  unsigned r = v.u + 0x7fffu + ((v.u >> 16) & 1u);
  return (u16)(r >> 16);
}

__device__ __forceinline__ float bf2f(u16 x) {
  union { unsigned u; float f; } v;
  v.u = ((unsigned)x) << 16;
  return v.f;
}

__device__ __forceinline__ u16 f2h(float x) {
  _Float16 h = (_Float16)x;
  return *(u16*)&h;
}

__device__ __forceinline__ unsigned pack2bf(float a, float b) {
  return (unsigned)f2bf(a) | ((unsigned)f2bf(b) << 16);
}

__device__ __forceinline__ float gelu_exact(float x) {
  return 0.5f * x * (1.0f + erff(x * 0.7071067811865475f));
}

__device__ __forceinline__ f32x4 mfma_16x16x32_bf16(u16x8 a, u16x8 b, f32x4 c) {
  asm("v_mfma_f32_16x16x32_bf16 %0, %1, %2, %0" : "+v"(c) : "v"(a), "v"(b));
  return c;
}

__device__ __forceinline__ float dot2h(h2 a, h2 b, float c) {
#ifdef HAVE_FDOT2
  return __builtin_amdgcn_fdot2(a, b, c, false);
#else
  return c + (float)a[0] * (float)b[0] + (float)a[1] * (float)b[1];
#endif
}

// Direct global->LDS DMA, 16B per lane.
__device__ __forceinline__ void gload_lds16(const u16* g, const u16* lds_base) {
  __builtin_amdgcn_global_load_lds(
      (const __attribute__((address_space(1))) unsigned int*)(uintptr_t)g,
      (__attribute__((address_space(3))) unsigned int*)(unsigned)(uintptr_t)lds_base,
      16, 0, 0);
}

__global__ __launch_bounds__(256) void split_kernel(const float* __restrict__ latents,
                                                    float* __restrict__ sp, float* __restrict__ gl) {
  int i = blockIdx.x * 256 + threadIdx.x;
  const int total = B * LT * D / 4;
  if (i >= total) return;
  float4 v = ((const float4*)latents)[i];
  int fi = i * 4;
  int d = fi % D;
  int row = fi / D;
  int l = row % LT;
  int b = row / LT;
  if (l < L) ((float4*)sp)[((size_t)(b * L + l) * D + d) / 4] = v;
  else ((float4*)gl)[((size_t)(b * G + (l - L)) * D + d) / 4] = v;
}

__global__ __launch_bounds__(256) void assemble_kernel(const float* __restrict__ sp,
                                                       const float* __restrict__ gl,
                                                       float* __restrict__ out) {
  int i = blockIdx.x * 256 + threadIdx.x;
  const int total = B * LT * D / 4;
  if (i >= total) return;
  int fi = i * 4;
  int d = fi % D;
  int row = fi / D;
  int l = row % LT;
  int b = row / LT;
  float4 v;
  if (l < L) v = ((const float4*)sp)[((size_t)(b * L + l) * D + d) / 4];
  else v = ((const float4*)gl)[((size_t)(b * G + (l - L)) * D + d) / 4];
  ((float4*)out)[i] = v;
}

// LayerNorm, bf16 output.
__global__ __launch_bounds__(256) void ln_kernel(const float* __restrict__ in,
                                                 const float* __restrict__ gw,
                                                 const float* __restrict__ bw,
                                                 u16* __restrict__ out) {
  int row = blockIdx.x;
  int t = threadIdx.x;
  const float* x = in + (size_t)row * D;
  float2 v = ((const float2*)x)[t];
  float s = v.x + v.y;
  float sq = v.x * v.x + v.y * v.y;
#pragma unroll
  for (int m = 1; m < 64; m <<= 1) {
    s += __shfl_xor(s, m, 64);
    sq += __shfl_xor(sq, m, 64);
  }
  __shared__ float ss[4], s2[4];
  int w = t >> 6;
  if ((t & 63) == 0) { ss[w] = s; s2[w] = sq; }
  __syncthreads();
  s = ss[0] + ss[1] + ss[2] + ss[3];
  sq = s2[0] + s2[1] + s2[2] + s2[3];
  float mean = s * (1.0f / D);
  float var = sq * (1.0f / D) - mean * mean;
  float rs = rsqrtf(var + 1e-5f);
  float2 gv = ((const float2*)gw)[t];
  float2 bv = ((const float2*)bw)[t];
  float ox = (v.x - mean) * rs * gv.x + bv.x;
  float oy = (v.y - mean) * rs * gv.y + bv.y;
  ((unsigned*)(out + (size_t)row * D))[t] = pack2bf(ox, oy);
}

// flat f32 -> bf16
__global__ __launch_bounds__(256) void cvt_bf16_kernel(const float* __restrict__ in,
                                                       u16* __restrict__ out, int n4) {
  int i = blockIdx.x * 256 + threadIdx.x;
  if (i >= n4) return;
  float4 v = ((const float4*)in)[i];
  ushort4 o;
  o.x = f2bf(v.x); o.y = f2bf(v.y); o.z = f2bf(v.z); o.w = f2bf(v.w);
  ((ushort4*)out)[i] = o;
}

// Transpose-convert weights: W fp32 [K][N] -> Wt bf16 [N][dstride] (cols 0..K-1 used).
struct WtJob { const float* src; u16* dst; int K; int N; int off; int dstride; };
struct WtJobs { WtJob j[16]; };

__global__ __launch_bounds__(256) void wt_convert_kernel(WtJobs jobs) {
  __shared__ float tile[32][33];
  int bid = blockIdx.x;
  int e = 0;
#pragma unroll
  for (int i = 1; i < 16; ++i) if (bid >= jobs.j[i].off) e = i;
  const WtJob& J = jobs.j[e];
  int ti = bid - J.off;
  int tiles_n = J.N >> 5;
  int tk = ti / tiles_n, tn = ti - tk * tiles_n;
  int t = threadIdx.x;
  int r = t >> 3, c4 = (t & 7) * 4;
  float4 v = *(const float4*)&J.src[(size_t)(tk * 32 + r) * J.N + tn * 32 + c4];
  tile[r][c4 + 0] = v.x; tile[r][c4 + 1] = v.y; tile[r][c4 + 2] = v.z; tile[r][c4 + 3] = v.w;
  __syncthreads();
  int r2 = t >> 3, k4 = (t & 7) * 4;
  ushort4 o;
  o.x = f2bf(tile[k4 + 0][r2]);
  o.y = f2bf(tile[k4 + 1][r2]);
  o.z = f2bf(tile[k4 + 2][r2]);
  o.w = f2bf(tile[k4 + 3][r2]);
  *(ushort4*)&J.dst[(size_t)(tn * 32 + r2) * J.dstride + tk * 32 + k4] = o;
}

// WQTt[(h*64+p)][c] = sum_d wkb[p][h*64+d] * wq[c][h*64+d]. grid (8h, 8ct).
__global__ __launch_bounds__(256) void comp_qt_kernel(const float* __restrict__ wq,
                                                      const float* __restrict__ wkb,
                                                      u16* __restrict__ out) {
  int h = blockIdx.x, ct = blockIdx.y;
  __shared__ float wk_s[64][68];
  __shared__ float wq_s[64][68];
  int t = threadIdx.x;
  int r = t >> 4, c4 = (t & 15) * 4;
#pragma unroll
  for (int i = 0; i < 4; ++i) {
    int rr = r + i * 16;
    *(float4*)&wk_s[rr][c4] = *(const float4*)&wkb[(size_t)rr * INNER + h * DH + c4];
    *(float4*)&wq_s[rr][c4] = *(const float4*)&wq[(size_t)(ct * 64 + rr) * INNER + h * DH + c4];
  }
  __syncthreads();
  int p = t >> 2, cb = (t & 3) * 16;
  float acc[16] = {};
  for (int d = 0; d < 64; ++d) {
    float a = wk_s[p][d];
#pragma unroll
    for (int j = 0; j < 16; ++j) acc[j] += a * wq_s[cb + j][d];
  }
  for (int j = 0; j < 16; ++j)
    out[(size_t)(h * 64 + p) * INNER + ct * 64 + cb + j] = f2bf(acc[j]);
}

// WO2t[j][512 + h*64 + p] = sum_d la_wo[h*64+d][j] * wvb[p][h*64+d]. grid (8h, 8jt).
__global__ __launch_bounds__(256) void comp_wo_kernel(const float* __restrict__ la_wo,
                                                      const float* __restrict__ wvb,
                                                      u16* __restrict__ WO2t) {
  int h = blockIdx.x, jt = blockIdx.y;
  __shared__ float lo_s[64][68];
  __shared__ float wv_s[64][68];
  int t = threadIdx.x;
  int r = t >> 4, c4 = (t & 15) * 4;
#pragma unroll
  for (int i = 0; i < 4; ++i) {
    int rr = r + i * 16;
    *(float4*)&lo_s[rr][c4] = *(const float4*)&la_wo[(size_t)(h * DH + rr) * D + jt * 64 + c4];
    *(float4*)&wv_s[rr][c4] = *(const float4*)&wvb[(size_t)rr * INNER + h * DH + c4];
  }
  __syncthreads();
  int j = t >> 2, pb = (t & 3) * 16;
  float acc[16] = {};
  for (int d = 0; d < 64; ++d) {
    float a = lo_s[d][j];
#pragma unroll
    for (int i = 0; i < 16; ++i) acc[i] += a * wv_s[pb + i][d];
  }
  for (int i = 0; i < 16; ++i)
    WO2t[(size_t)(jt * 64 + j) * 1024 + 512 + h * DH + pb + i] = f2bf(acc[i]);
}

// bf16 MFMA GEMM v3: ds_read(cur)->regs FIRST, then DMA-prefetch(next), then MFMA.
struct WSet { const u16* W[4]; void* out[4]; };

template <int BM, int BN>
__global__ __launch_bounds__(256) void gemm_v3_kernel(const u16* __restrict__ A, WSet gs,
                                                      const float* __restrict__ bias,
                                                      const float* __restrict__ res,
                                                      u16* __restrict__ out_bf,
                                                      int M, int K, int N, int act, unsigned obf) {
  constexpr int FM = BM / 32;
  constexpr int FN = BN / 32;
  __shared__ u16 As[2][BM * 64];
  __shared__ u16 Bs[2][BN * 64];
  int t = threadIdx.x;
  int wave = __builtin_amdgcn_readfirstlane(t >> 6);
  int lane = t & 63;
  int wr = wave >> 1, wc = wave & 1;
  int row16 = lane & 15, katom = lane >> 4;
  int bm = blockIdx.y * BM, bn = blockIdx.x * BN;
  const u16* W = gs.W[blockIdx.z];
  void* outp = gs.out[blockIdx.z];
  unsigned obz = (obf >> (blockIdx.z * 2)) & 3u;
  int srow = lane >> 3;
  int sg = lane & 7;
  int swz = row16 & 7;
  f32x4 acc[FM][FN] = {};

  auto stage = [&](int buf, int kb) {
#pragma unroll
    for (int c = 0; c < BM / 32; ++c) {
      int rowbase = wave * (BM / 4) + c * 8;
      int row = rowbase + srow;
      int gsrc = sg ^ (row & 7);
      gload_lds16(&A[(size_t)(bm + row) * K + kb + gsrc * 8], &As[buf][rowbase * 64]);
    }
#pragma unroll
    for (int c = 0; c < BN / 32; ++c) {
      int rowbase = wave * (BN / 4) + c * 8;
      int row = rowbase + srow;
      int gsrc = sg ^ (row & 7);
      gload_lds16(&W[(size_t)(bn + row) * K + kb + gsrc * 8], &Bs[buf][rowbase * 64]);
    }
  };

  stage(0, 0);
  __syncthreads();
  int nk = K >> 6;
  int cur = 0;
  for (int ti = 0; ti < nk; ++ti) {
    u16x8 af[2][FM], bf[2][FN];
#pragma unroll
    for (int kk = 0; kk < 2; ++kk) {
#pragma unroll
      for (int m = 0; m < FM; ++m) {
        int r = wr * (BM / 2) + m * 16 + row16;
        af[kk][m] = *(u16x8*)&As[cur][r * 64 + ((kk * 4 + katom) ^ swz) * 8];
      }
#pragma unroll
      for (int n = 0; n < FN; ++n) {
        int r = wc * (BN / 2) + n * 16 + row16;
        bf[kk][n] = *(u16x8*)&Bs[cur][r * 64 + ((kk * 4 + katom) ^ swz) * 8];
      }
    }
    __builtin_amdgcn_sched_barrier(0);
    if (ti + 1 < nk) stage(cur ^ 1, (ti + 1) << 6);
#pragma unroll
    for (int kk = 0; kk < 2; ++kk)
#pragma unroll
      for (int m = 0; m < FM; ++m)
#pragma unroll
        for (int n = 0; n < FN; ++n)
          acc[m][n] = mfma_16x16x32_bf16(af[kk][m], bf[kk][n], acc[m][n]);
    __syncthreads();
    cur ^= 1;
  }
#pragma unroll
  for (int m = 0; m < FM; ++m) {
    int row = bm + wr * (BM / 2) + m * 16 + katom * 4;
#pragma unroll
    for (int n = 0; n < FN; ++n) {
      int col = bn + wc * (BN / 2) + n * 16 + row16;
      float bsv = bias ? bias[col] : 0.f;
#pragma unroll
      for (int r = 0; r < 4; ++r) {
        float v = acc[m][n][r] + bsv;
        if (act) v = gelu_exact(v);
        size_t oi = (size_t)(row + r) * N + col;
        if (res) v += res[oi];
        if (obz == 1) ((u16*)outp)[oi] = f2bf(v);
        else if (obz == 3) ((u16*)outp)[oi] = f2h(v);
        else {
          ((float*)outp)[oi] = v;
          if (obz == 2) out_bf[oi] = f2bf(v);
        }
      }
    }
  }
}

// Local KNN attention v4: Q,TQ bf16; K,V fp16. Chain-split accumulators; ar
// computation merged into the V-gather phase (hides LDS/VALU under gathers).
// Writes OA = [o_gather | ar] bf16.
__global__ __launch_bounds__(256) void local_attn2_kernel(
    const u16* __restrict__ Qh, const u16* __restrict__ Kh, const u16* __restrict__ Vh,
    const u16* __restrict__ TQh, const float* __restrict__ rpe, const float* __restrict__ dist,
    const int* __restrict__ idx, const float* __restrict__ lsig, u16* __restrict__ OA) {
  int blk = blockIdx.x;
  int b = blk >> 11;
  int t = threadIdx.x;
  __shared__ _Float16 q_s[INNER];
  __shared__ float tq_s[INNER];
  __shared__ float rpe_s[KN][68];
  __shared__ float a_s[H][KN + 1];
  __shared__ int idx_s[KN];
  __shared__ float dist_s[KN];
  __shared__ float sig_s[H];
  size_t row = (size_t)blk;
  {
    unsigned qp = ((const unsigned*)(Qh + row * INNER))[t];
    q_s[2 * t] = (_Float16)bf2f((u16)qp);
    q_s[2 * t + 1] = (_Float16)bf2f((u16)(qp >> 16));
    unsigned tp = ((const unsigned*)(TQh + row * INNER))[t];
    tq_s[2 * t] = bf2f((u16)tp);
    tq_s[2 * t + 1] = bf2f((u16)(tp >> 16));
  }
  {
    const float* rp = rpe + row * (KN * PE);
    int k = t >> 3, p0 = (t & 7) * 8;
    *(float4*)&rpe_s[k][p0] = *(const float4*)&rp[k * PE + p0];
    *(float4*)&rpe_s[k][p0 + 4] = *(const float4*)&rp[k * PE + p0 + 4];
  }
  if (t < KN) {
    idx_s[t] = idx[row * KN + t];
    dist_s[t] = dist[row * KN + t];
  }
  if (t < H) sig_s[t] = expf(2.0f * lsig[t]);
  __syncthreads();
  {
    int h = t >> 5, k = t & 31;
    int rr = idx_s[k];
    const u16* krow = Kh + ((size_t)(b * L + rr)) * INNER + h * DH;
    // 4 independent fdot2 chains of length 8
    float ac0 = 0.f, ac1 = 0.f, ac2 = 0.f, ac3 = 0.f;
#pragma unroll
    for (int i = 0; i < 8; ++i) {
      u16x8 kv = *(const u16x8*)&krow[i * 8];
      u16x8 qv = *(const u16x8*)&q_s[h * DH + i * 8];
      const h2* kk = (const h2*)&kv;
      const h2* qq = (const h2*)&qv;
      ac0 = dot2h(kk[0], qq[0], ac0);
      ac1 = dot2h(kk[1], qq[1], ac1);
      ac2 = dot2h(kk[2], qq[2], ac2);
      ac3 = dot2h(kk[3], qq[3], ac3);
    }
    float acc = (ac0 + ac1) + (ac2 + ac3);
    // 2 independent chains for the rpe*tq term
    float ar0 = 0.f, ar1 = 0.f;
    const float* tqh = tq_s + h * DH;
#pragma unroll
    for (int p = 0; p < PE; p += 8) {
      float4 r4a = *(float4*)&rpe_s[k][p];
      float4 t4a = *(const float4*)&tqh[p];
      float4 r4b = *(float4*)&rpe_s[k][p + 4];
      float4 t4b = *(const float4*)&tqh[p + 4];
      ar0 += r4a.x * t4a.x + r4a.y * t4a.y + r4a.z * t4a.z + r4a.w * t4a.w;
      ar1 += r4b.x * t4b.x + r4b.y * t4b.y + r4b.z * t4b.z + r4b.w * t4b.w;
    }
    float accr = ar0 + ar1;
    float dd = dist_s[k];
    float logit = SCALE * (acc + accr) - dd * dd / (2.0f * sig_s[h]);
    float mx = logit;
#pragma unroll
    for (int m = 1; m < 32; m <<= 1) mx = fmaxf(mx, __shfl_xor(mx, m, 64));
    float e = expf(logit - mx);
    float sum = e;
#pragma unroll
    for (int m = 1; m < 32; m <<= 1) sum += __shfl_xor(sum, m, 64);
    a_s[h][k] = e / sum;
  }
  __syncthreads();
  {
    // Merged V-gather + ar phase. Thread t: head h0 = t>>5, output dims (2t, 2t+1),
    // ar dims p0 = 2*(t&31), p0+1 of head h0.
    int h0 = t >> 5, j = t & 31;
    const u16* vbase = Vh + (size_t)b * L * INNER + 2 * t;
    h2 oA, oB;
    oA[0] = (_Float16)0.f; oA[1] = (_Float16)0.f;
    oB[0] = (_Float16)0.f; oB[1] = (_Float16)0.f;
    float ax0 = 0.f, ay0 = 0.f, ax1 = 0.f, ay1 = 0.f;  // 2 chains x 2 dims
#pragma unroll
    for (int k = 0; k < KN; k += 2) {
      unsigned vv0 = *(const unsigned*)&vbase[(size_t)idx_s[k] * INNER];
      unsigned vv1 = *(const unsigned*)&vbase[(size_t)idx_s[k + 1] * INNER];
      float aw0 = a_s[h0][k];
      float aw1 = a_s[h0][k + 1];
      float2 r0 = *(float2*)&rpe_s[k][2 * j];
      float2 r1 = *(float2*)&rpe_s[k + 1][2 * j];
      h2 a2_0, a2_1;
      a2_0[0] = (_Float16)aw0; a2_0[1] = (_Float16)aw0;
      a2_1[0] = (_Float16)aw1; a2_1[1] = (_Float16)aw1;
      oA = a2_0 * (*(h2*)&vv0) + oA;
      oB = a2_1 * (*(h2*)&vv1) + oB;
      ax0 += aw0 * r0.x;
      ay0 += aw0 * r0.y;
      ax1 += aw1 * r1.x;
      ay1 += aw1 * r1.y;
    }
    h2 o2 = oA + oB;
    ((unsigned*)&OA[row * 1024])[t] = pack2bf((float)o2[0], (float)o2[1]);
    ((unsigned*)&OA[row * 1024 + 512])[t] = pack2bf(ax0 + ax1, ay0 + ay1);
  }
}

// spatial->global cross attention, MFMA version.
__global__ __launch_bounds__(256) void s2g_attn_mfma_kernel(const u16* __restrict__ Qh,
                                                            const u16* __restrict__ Kg,
                                                            const u16* __restrict__ Vg,
                                                            u16* __restrict__ O) {
  int l0 = blockIdx.x * 64;
  int h = blockIdx.y;
  int b = blockIdx.z;
  int t = threadIdx.x;
  int wave = __builtin_amdgcn_readfirstlane(t >> 6);
  int lane = t & 63;
  int wr = wave >> 1, wc = wave & 1;
  int row16 = lane & 15, katom = lane >> 4;
  __shared__ u16 Qs[64 * 72];
  __shared__ u16 Ks[128 * 72];
  __shared__ u16 Ps[64 * 136];
  __shared__ float redm[2][64], reds[2][64];
  u16* VT = Ks;

  for (int i = t; i < 512; i += 256) {
    int r = i >> 3, s = i & 7;
    *(u16x8*)&Qs[r * 72 + s * 8] = *(const u16x8*)&Qh[((size_t)(b * L + l0 + r)) * INNER + h * DH + s * 8];
  }
  for (int i = t; i < 1024; i += 256) {
    int r = i >> 3, s = i & 7;
    *(u16x8*)&Ks[r * 72 + s * 8] = *(const u16x8*)&Kg[((size_t)(b * G + r)) * INNER + h * DH + s * 8];
  }
  __syncthreads();

  f32x4 acc[2][4] = {};
#pragma unroll
  for (int kk = 0; kk < 2; ++kk) {
    u16x8 af[2], bf[4];
#pragma unroll
    for (int m = 0; m < 2; ++m)
      af[m] = *(u16x8*)&Qs[(wr * 32 + m * 16 + row16) * 72 + kk * 32 + katom * 8];
#pragma unroll
    for (int n = 0; n < 4; ++n)
      bf[n] = *(u16x8*)&Ks[(wc * 64 + n * 16 + row16) * 72 + kk * 32 + katom * 8];
#pragma unroll
    for (int m = 0; m < 2; ++m)
#pragma unroll
      for (int n = 0; n < 4; ++n) acc[m][n] = mfma_16x16x32_bf16(af[m], bf[n], acc[m][n]);
  }
#pragma unroll
  for (int m = 0; m < 2; ++m)
#pragma unroll
    for (int n = 0; n < 4; ++n)
#pragma unroll
      for (int r = 0; r < 4; ++r) acc[m][n][r] *= SCALE;

  float mx[2][4];
#pragma unroll
  for (int m = 0; m < 2; ++m)
#pragma unroll
    for (int r = 0; r < 4; ++r) {
      float v = fmaxf(fmaxf(acc[m][0][r], acc[m][1][r]), fmaxf(acc[m][2][r], acc[m][3][r]));
#pragma unroll
      for (int msk = 1; msk < 16; msk <<= 1) v = fmaxf(v, __shfl_xor(v, msk, 64));
      mx[m][r] = v;
    }
  if (row16 == 0) {
#pragma unroll
    for (int m = 0; m < 2; ++m)
#pragma unroll
      for (int r = 0; r < 4; ++r) redm[wc][wr * 32 + m * 16 + katom * 4 + r] = mx[m][r];
  }
  __syncthreads();

  {
    int m = t >> 1, ch = t & 1;
    const u16* vrow = Vg + ((size_t)(b * G + m)) * INNER + h * DH + ch * 32;
#pragma unroll
    for (int j = 0; j < 8; ++j) {
      ushort4 v = *(const ushort4*)&vrow[j * 4];
      int c = ch * 32 + j * 4;
      VT[(c + 0) * 136 + m] = v.x;
      VT[(c + 1) * 136 + m] = v.y;
      VT[(c + 2) * 136 + m] = v.z;
      VT[(c + 3) * 136 + m] = v.w;
    }
  }

  float sm[2][4];
#pragma unroll
  for (int m = 0; m < 2; ++m)
#pragma unroll
    for (int r = 0; r < 4; ++r) {
      int qi = wr * 32 + m * 16 + katom * 4 + r;
      float gm = fmaxf(redm[0][qi], redm[1][qi]);
      float s = 0.f;
#pragma unroll
      for (int n = 0; n < 4; ++n) {
        float e = expf(acc[m][n][r] - gm);
        acc[m][n][r] = e;
        s += e;
      }
#pragma unroll
      for (int msk = 1; msk < 16; msk <<= 1) s += __shfl_xor(s, msk, 64);
      sm[m][r] = s;
    }
  if (row16 == 0) {
#pragma unroll
    for (int m = 0; m < 2; ++m)
#pragma unroll
      for (int r = 0; r < 4; ++r) reds[wc][wr * 32 + m * 16 + katom * 4 + r] = sm[m][r];
  }
  __syncthreads();

#pragma unroll
  for (int m = 0; m < 2; ++m)
#pragma unroll
    for (int r = 0; r < 4; ++r) {
      int qi = wr * 32 + m * 16 + katom * 4 + r;
      float inv = 1.0f / (reds[0][qi] + reds[1][qi]);
#pragma unroll
      for (int n = 0; n < 4; ++n)
        Ps[qi * 136 + wc * 64 + n * 16 + row16] = f2bf(acc[m][n][r] * inv);
    }
  __syncthreads();

  f32x4 oacc[2][2] = {};
#pragma unroll
  for (int kk = 0; kk < 4; ++kk) {
    u16x8 pa[2], vb[2];
#pragma unroll
    for (int m = 0; m < 2; ++m)
      pa[m] = *(u16x8*)&Ps[(wr * 32 + m * 16 + row16) * 136 + kk * 32 + katom * 8];
#pragma unroll
    for (int n = 0; n < 2; ++n)
      vb[n] = *(u16x8*)&VT[(wc * 32 + n * 16 + row16) * 136 + kk * 32 + katom * 8];
#pragma unroll
    for (int m = 0; m < 2; ++m)
#pragma unroll
      for (int n = 0; n < 2; ++n) oacc[m][n] = mfma_16x16x32_bf16(pa[m], vb[n], oacc[m][n]);
  }
#pragma unroll
  for (int m = 0; m < 2; ++m) {
    int q = wr * 32 + m * 16 + katom * 4;
#pragma unroll
    for (int n = 0; n < 2; ++n) {
      int d = wc * 32 + n * 16 + row16;
#pragma unroll
      for (int r = 0; r < 4; ++r)
        O[((size_t)(b * L + l0 + q + r)) * INNER + h * DH + d] = f2bf(oacc[m][n][r]);
    }
  }
}

// ---------------- g2s: 5-phase MFMA pipeline ----------------
__global__ __launch_bounds__(256) void g2s_logits_kernel(const u16* __restrict__ QGh,
                                                         const u16* __restrict__ KBh,
                                                         float* __restrict__ LG) {
  __shared__ u16 Qs[128 * 72];
  __shared__ u16 Ks[128 * 72];
  int nt = blockIdx.x, h = blockIdx.y, b = blockIdx.z;
  int t = threadIdx.x;
  int wave = t >> 6, lane = t & 63;
  int row16 = lane & 15, katom = lane >> 4;
#pragma unroll
  for (int i = 0; i < 4; ++i) {
    int row = (t >> 3) + i * 32;
    int cg = t & 7;
    *(u16x8*)&Qs[row * 72 + cg * 8] =
        *(const u16x8*)&QGh[((size_t)(b * G + row)) * INNER + h * DH + cg * 8];
    *(u16x8*)&Ks[row * 72 + cg * 8] =
        *(const u16x8*)&KBh[((size_t)(b * L + nt * 128 + row)) * INNER + h * DH + cg * 8];
  }
  __syncthreads();
  f32x4 acc[2][8] = {};
#pragma unroll
  for (int kk = 0; kk < 2; ++kk) {
    u16x8 af[2], bf[8];
#pragma unroll
    for (int qt = 0; qt < 2; ++qt)
      af[qt] = *(u16x8*)&Qs[(wave * 32 + qt * 16 + row16) * 72 + kk * 32 + katom * 8];
#pragma unroll
    for (int nm = 0; nm < 8; ++nm)
      bf[nm] = *(u16x8*)&Ks[(nm * 16 + row16) * 72 + kk * 32 + katom * 8];
#pragma unroll
    for (int qt = 0; qt < 2; ++qt)
#pragma unroll
      for (int nm = 0; nm < 8; ++nm) acc[qt][nm] = mfma_16x16x32_bf16(af[qt], bf[nm], acc[qt][nm]);
  }
#pragma unroll
  for (int qt = 0; qt < 2; ++qt) {
    int g = wave * 32 + qt * 16 + katom * 4;
#pragma unroll
    for (int nm = 0; nm < 8; ++nm) {
      int m = nt * 128 + nm * 16 + row16;
#pragma unroll
      for (int r = 0; r < 4; ++r)
        LG[(((size_t)(b * H + h) * G) + g + r) * L + m] = acc[qt][nm][r] * SCALE;
    }
  }
}

__global__ __launch_bounds__(256) void g2s_softmax_kernel(const float* __restrict__ LG,
                                                          u16* __restrict__ WG) {
  int g = blockIdx.x & (G - 1);
  int b = blockIdx.x >> 7;
  int t = threadIdx.x;
  int w = t >> 6, lane = t & 63;
  __shared__ float red[8];
  for (int h = 0; h < H; ++h) {
    size_t base = (((size_t)(b * H + h) * G) + g) * L;
    float4 lo = *(const float4*)&LG[base + t * 8];
    float4 hi = *(const float4*)&LG[base + t * 8 + 4];
    float mx = fmaxf(fmaxf(fmaxf(lo.x, lo.y), fmaxf(lo.z, lo.w)),
                     fmaxf(fmaxf(hi.x, hi.y), fmaxf(hi.z, hi.w)));
#pragma unroll
    for (int m = 1; m < 64; m <<= 1) mx = fmaxf(mx, __shfl_xor(mx, m, 64));
    if (lane == 0) red[w] = mx;
    __syncthreads();
    mx = fmaxf(fmaxf(red[0], red[1]), fmaxf(red[2], red[3]));
    float e[8];
    e[0] = expf(lo.x - mx); e[1] = expf(lo.y - mx); e[2] = expf(lo.z - mx); e[3] = expf(lo.w - mx);
    e[4] = expf(hi.x - mx); e[5] = expf(hi.y - mx); e[6] = expf(hi.z - mx); e[7] = expf(hi.w - mx);
    float sum = e[0] + e[1] + e[2] + e[3] + e[4] + e[5] + e[6] + e[7];
#pragma unroll
    for (int m = 1; m < 64; m <<= 1) sum += __shfl_xor(sum, m, 64);
    if (lane == 0) red[4 + w] = sum;
    __syncthreads();
    float inv = 1.0f / (red[4] + red[5] + red[6] + red[7]);
    ushort4 o0, o1;
    o0.x = f2bf(e[0] * inv); o0.y = f2bf(e[1] * inv); o0.z = f2bf(e[2] * inv); o0.w = f2bf(e[3] * inv);
    o1.x = f2bf(e[4] * inv); o1.y = f2bf(e[5] * inv); o1.z = f2bf(e[6] * inv); o1.w = f2bf(e[7] * inv);
    *(ushort4*)&WG[base + t * 8] = o0;
    *(ushort4*)&WG[base + t * 8 + 4] = o1;
    __syncthreads();
  }
}

__global__ __launch_bounds__(256) void g2s_vt_kernel(const u16* __restrict__ VBh,
                                                     u16* __restrict__ Vt) {
  __shared__ u16 tile[32][36];
  int mt = blockIdx.x, ct = blockIdx.y, b = blockIdx.z;
  int t = threadIdx.x;
  int r = t >> 3, c4 = (t & 7) * 4;
  *(ushort4*)&tile[r][c4] =
      *(const ushort4*)&VBh[((size_t)(b * L + mt * 32 + r)) * INNER + ct * 32 + c4];
  __syncthreads();
  int r2 = t >> 3, m4 = (t & 7) * 4;
  int c = ct * 32 + r2;
  int h = c >> 6, d = c & 63;
  ushort4 o;
  o.x = tile[m4 + 0][r2]; o.y = tile[m4 + 1][r2]; o.z = tile[m4 + 2][r2]; o.w = tile[m4 + 3][r2];
  *(ushort4*)&Vt[(((size_t)(b * H + h) * DH) + d) * L + mt * 32 + m4] = o;
}

__global__ __launch_bounds__(256) void g2s_pv_kernel(const u16* __restrict__ WG,
                                                     const u16* __restrict__ Vt,
                                                     float* __restrict__ Opart) {
  __shared__ u16 Ws[128 * 40];
  __shared__ u16 Vs[64 * 40];
  int s = blockIdx.x, h = blockIdx.y, b = blockIdx.z;
  int t = threadIdx.x;
  int wave = t >> 6, lane = t & 63;
  int row16 = lane & 15, katom = lane >> 4;
  int r0 = t >> 2, cg = t & 3;
  size_t wbase = ((size_t)(b * H + h) * G) * L;
  size_t vbase = ((size_t)(b * H + h) * DH) * L;
  f32x4 acc[2][4] = {};
  for (int it = 0; it < 8; ++it) {
    int m0 = s * 256 + it * 32;
    u16x8 w0 = *(const u16x8*)&WG[wbase + (size_t)r0 * L + m0 + cg * 8];
    u16x8 w1 = *(const u16x8*)&WG[wbase + (size_t)(r0 + 64) * L + m0 + cg * 8];
    u16x8 v0 = *(const u16x8*)&Vt[vbase + (size_t)(t >> 2) * L + m0 + cg * 8];
    __syncthreads();
    *(u16x8*)&Ws[r0 * 40 + cg * 8] = w0;
    *(u16x8*)&Ws[(r0 + 64) * 40 + cg * 8] = w1;
    *(u16x8*)&Vs[(t >> 2) * 40 + cg * 8] = v0;
    __syncthreads();
    u16x8 af[2], bf[4];
#pragma unroll
    for (int qt = 0; qt < 2; ++qt)
      af[qt] = *(u16x8*)&Ws[(wave * 32 + qt * 16 + row16) * 40 + katom * 8];
#pragma unroll
    for (int nd = 0; nd < 4; ++nd)
      bf[nd] = *(u16x8*)&Vs[(nd * 16 + row16) * 40 + katom * 8];
#pragma unroll
    for (int qt = 0; qt < 2; ++qt)
#pragma unroll
      for (int nd = 0; nd < 4; ++nd) acc[qt][nd] = mfma_16x16x32_bf16(af[qt], bf[nd], acc[qt][nd]);
  }
  size_t obase = (((size_t)(b * H + h) * 8) + s) * G * DH;
#pragma unroll
  for (int qt = 0; qt < 2; ++qt) {
    int g = wave * 32 + qt * 16 + katom * 4;
#pragma unroll
    for (int nd = 0; nd < 4; ++nd) {
      int d = nd * 16 + row16;
#pragma unroll
      for (int r = 0; r < 4; ++r) Opart[obase + (size_t)(g + r) * DH + d] = acc[qt][nd][r];
    }
  }
}

__global__ __launch_bounds__(256) void g2s_combine_kernel(const float* __restrict__ Opart,
                                                          u16* __restrict__ OGh) {
  int g = blockIdx.x & (G - 1);
  int b = blockIdx.x >> 7;
  int t = threadIdx.x;
  int h = t >> 5, d0 = (t & 31) * 2;
  float o0 = 0.f, o1 = 0.f;
#pragma unroll
  for (int s = 0; s < 8; ++s) {
    const float* p = Opart + ((((size_t)(b * H + h) * 8) + s) * G + g) * DH + d0;
    o0 += p[0];
    o1 += p[1];
  }
  *(unsigned*)&OGh[((size_t)(b * G + g)) * INNER + h * DH + d0] = pack2bf(o0, o1);
}

}  // namespace

extern "C" void kernel_launch(void* const* d_in, const int* in_sizes, int n_in,
                              void* d_out, int out_size, void* d_ws, size_t ws_size,
                              hipStream_t stream) {
  (void)in_sizes; (void)n_in; (void)out_size; (void)ws_size;
  const float* latents = (const float*)d_in[0];
  const float* rpe = (const float*)d_in[1];
  const float* dist = (const float*)d_in[2];
  const float* sn_g = (const float*)d_in[3];
  const float* sn_b = (const float*)d_in[4];
  const float* la_wq = (const float*)d_in[5];
  const float* la_wk = (const float*)d_in[6];
  const float* la_wv = (const float*)d_in[7];
  const float* la_wo = (const float*)d_in[8];
  const float* la_bo = (const float*)d_in[9];
  const float* log_sigma = (const float*)d_in[10];
  const float* scn_g = (const float*)d_in[11];
  const float* scn_b = (const float*)d_in[12];
  const float* s2g_wq = (const float*)d_in[13];
  const float* s2g_wk = (const float*)d_in[14];
  const float* s2g_wv = (const float*)d_in[15];
  const float* s2g_wo = (const float*)d_in[16];
  const float* s2g_bo = (const float*)d_in[17];
  const float* gcn_g = (const float*)d_in[18];
  const float* gcn_b = (const float*)d_in[19];
  const float* g2s_wq = (const float*)d_in[20];
  const float* g2s_wk = (const float*)d_in[21];
  const float* g2s_wv = (const float*)d_in[22];
  const float* g2s_wo = (const float*)d_in[23];
  const float* g2s_bo = (const float*)d_in[24];
  const float* gfn_g = (const float*)d_in[25];
  const float* gfn_b = (const float*)d_in[26];
  const float* gff_w1 = (const float*)d_in[27];
  const float* gff_b1 = (const float*)d_in[28];
  const float* gff_w2 = (const float*)d_in[29];
  const float* gff_b2 = (const float*)d_in[30];
  const float* sfn_g = (const float*)d_in[31];
  const float* sfn_b = (const float*)d_in[32];
  const float* sff_w1 = (const float*)d_in[33];
  const float* sff_b1 = (const float*)d_in[34];
  const float* sff_w2 = (const float*)d_in[35];
  const float* sff_b2 = (const float*)d_in[36];
  const int* topk = (const int*)d_in[37];
  const float* wkb = la_wk + (size_t)D * INNER;
  const float* wvb = la_wv + (size_t)D * INNER;

  // ---- workspace layout ----
  char* wsb = (char*)d_ws;
  size_t off = 0;
  auto alloc = [&](size_t bytes) {
    char* p = wsb + off;
    off += (bytes + 255) & ~(size_t)255;
    return p;
  };
  const size_t SPn = (size_t)B * L * D;
  const size_t GLn = (size_t)B * G * D;
  float* SP = (float*)alloc(SPn * 4);
  float* GL = (float*)alloc(GLn * 4);
  float* QB = (float*)alloc(SPn * 4);
  float* KB = (float*)alloc(SPn * 4);
  float* VB = (float*)alloc(SPn * 4);
  float* S1 = (float*)alloc(SPn * 4);
  float* S2 = (float*)alloc(SPn * 4);
  float* G1 = (float*)alloc(GLn * 4);
  float* G2 = (float*)alloc(GLn * 4);
  float* QG = (float*)alloc(GLn * 4);
  float* KG = (float*)alloc(GLn * 4);
  float* VG = (float*)alloc(GLn * 4);
  u16* XNh = (u16*)alloc(SPn * 2);
  u16* OBh = (u16*)alloc(SPn * 2);
  u16* S2h = (u16*)alloc(SPn * 2);
  u16* HSh = (u16*)alloc((size_t)B * L * FF * 2);
  u16* GLh = (u16*)alloc(GLn * 2);
  u16* GNh = (u16*)alloc(GLn * 2);
  u16* OGh = (u16*)alloc(GLn * 2);
  u16* HGh = (u16*)alloc((size_t)B * G * FF * 2);
  const size_t SQ = 512 * 512, BIG = 512 * 2048;
  u16* WT = (u16*)alloc((12 * SQ + 4 * BIG) * 2);
  u16* la_wq_t = WT + 0 * SQ;
  u16* la_wk_t = WT + 1 * SQ;
  u16* la_wv_t = WT + 2 * SQ;
  u16* s2g_wq_t = WT + 4 * SQ;
  u16* s2g_wk_t = WT + 5 * SQ;
  u16* s2g_wv_t = WT + 6 * SQ;
  u16* s2g_wo_t = WT + 7 * SQ;
  u16* g2s_wq_t = WT + 8 * SQ;
  u16* g2s_wk_t = WT + 9 * SQ;
  u16* g2s_wv_t = WT + 10 * SQ;
  u16* g2s_wo_t = WT + 11 * SQ;
  u16* gff1_t = WT + 12 * SQ;
  u16* gff2_t = WT + 12 * SQ + BIG;
  u16* sff1_t = WT + 12 * SQ + 2 * BIG;
  u16* sff2_t = WT + 12 * SQ + 3 * BIG;
  u16* WQTt = (u16*)alloc(SQ * 2);
  u16* WO2t = (u16*)alloc(512 * 1024 * 2);

  // local-path bf16/fp16 aliases
  u16* lkh = (u16*)KB;
  u16* lvh = (u16*)KB + SPn;
  u16* ltqh = (u16*)VB;
  u16* lqh = (u16*)VB + SPn;
  u16* OA = (u16*)QB;

  // s2g aliases
  u16* QBh = (u16*)QB;
  u16* KGh = (u16*)KG;
  u16* VGh = (u16*)VG;

  // g2s aliases over dead regions (stream-sequential => safe)
  float* LG = KB;
  u16* WG = (u16*)S1;
  u16* KBh = (u16*)QB;
  u16* VBh = (u16*)QB + SPn;
  u16* QGh = HSh;
  u16* Vt = HSh + GLn;
  float* Opart = (float*)(HSh + GLn + (size_t)B * H * DH * L);

  const int threads = 256;
  int nsplit = (B * LT * D / 4 + 255) / 256;

  split_kernel<<<nsplit, threads, 0, stream>>>(latents, SP, GL);

  // ---- weight transpose-convert + composite weights ----
  {
    WtJobs jobs;
    auto set = [&](int i, const float* s, u16* d, int K, int N, int offv, int dstride) {
      jobs.j[i].src = s; jobs.j[i].dst = d; jobs.j[i].K = K; jobs.j[i].N = N;
      jobs.j[i].off = offv; jobs.j[i].dstride = dstride;
    };
    int o = 0;
    set(0, la_wq, la_wq_t, 512, 512, o, 512); o += 256;
    set(1, la_wk, la_wk_t, 512, 512, o, 512); o += 256;
    set(2, la_wv, la_wv_t, 512, 512, o, 512); o += 256;
    set(3, la_wo, WO2t, 512, 512, o, 1024); o += 256;
    set(4, s2g_wq, s2g_wq_t, 512, 512, o, 512); o += 256;
    set(5, s2g_wk, s2g_wk_t, 512, 512, o, 512); o += 256;
    set(6, s2g_wv, s2g_wv_t, 512, 512, o, 512); o += 256;
    set(7, s2g_wo, s2g_wo_t, 512, 512, o, 512); o += 256;
    set(8, g2s_wq, g2s_wq_t, 512, 512, o, 512); o += 256;
    set(9, g2s_wk, g2s_wk_t, 512, 512, o, 512); o += 256;
    set(10, g2s_wv, g2s_wv_t, 512, 512, o, 512); o += 256;
    set(11, g2s_wo, g2s_wo_t, 512, 512, o, 512); o += 256;
    set(12, gff_w1, gff1_t, 512, 2048, o, 512); o += 1024;
    set(13, gff_w2, gff2_t, 2048, 512, o, 2048); o += 1024;
    set(14, sff_w1, sff1_t, 512, 2048, o, 512); o += 1024;
    set(15, sff_w2, sff2_t, 2048, 512, o, 2048); o += 1024;
    wt_convert_kernel<<<o, threads, 0, stream>>>(jobs);
  }
  comp_qt_kernel<<<dim3(8, 8), threads, 0, stream>>>(la_wq, wkb, WQTt);
  comp_wo_kernel<<<dim3(8, 8), threads, 0, stream>>>(la_wo, wvb, WO2t);

  auto gemm = [&](const u16* A, const u16* Wt, const float* bias, const float* res,
                  void* out, int M, int K, int N, int act, unsigned obf, u16* out_bf) {
    WSet gs{};
    gs.W[0] = Wt; gs.out[0] = out;
    if (N >= 1024)
      gemm_v3_kernel<64, 128><<<dim3(N / 128, M / 64, 1), threads, 0, stream>>>(
          A, gs, bias, res, out_bf, M, K, N, act, obf);
    else
      gemm_v3_kernel<64, 64><<<dim3(N / 64, M / 64, 1), threads, 0, stream>>>(
          A, gs, bias, res, out_bf, M, K, N, act, obf);
  };
  auto gemm_multi = [&](const u16* A, const u16* W0, const u16* W1, const u16* W2, const u16* W3,
                        void* o0, void* o1, void* o2, void* o3, int nw, int M, int K, int N,
                        unsigned obf) {
    WSet gs{};
    gs.W[0] = W0; gs.W[1] = W1; gs.W[2] = W2; gs.W[3] = W3;
    gs.out[0] = o0; gs.out[1] = o1; gs.out[2] = o2; gs.out[3] = o3;
    gemm_v3_kernel<64, 64><<<dim3(N / 64, M / 64, nw), threads, 0, stream>>>(
        A, gs, nullptr, nullptr, nullptr, M, K, N, 0, obf);
  };

  // --- local KNN attention block ---
  ln_kernel<<<B * L, threads, 0, stream>>>(SP, sn_g, sn_b, XNh);
  // obf per z: Q bf16(1), K fp16(3), V fp16(3), TQ bf16(1)
  gemm_multi(XNh, la_wq_t, la_wk_t, la_wv_t, WQTt, lqh, lkh, lvh, ltqh, 4, B * L, D, INNER,
             1u | (3u << 2) | (3u << 4) | (1u << 6));
  local_attn2_kernel<<<B * L, threads, 0, stream>>>(lqh, lkh, lvh, ltqh, rpe, dist, topk,
                                                    log_sigma, OA);
  gemm(OA, WO2t, la_bo, SP, S1, B * L, 1024, D, 0, 0, nullptr);

  // --- spatial -> global cross attention (MFMA) ---
  ln_kernel<<<B * L, threads, 0, stream>>>(S1, scn_g, scn_b, XNh);
  gemm(XNh, s2g_wq_t, nullptr, nullptr, QBh, B * L, D, INNER, 0, 1, nullptr);
  cvt_bf16_kernel<<<(int)(GLn / 4 + 255) / 256, threads, 0, stream>>>(GL, GLh, (int)(GLn / 4));
  gemm_multi(GLh, s2g_wk_t, s2g_wv_t, nullptr, nullptr, KGh, VGh, nullptr, nullptr, 2, B * G, D, INNER,
             1u | (1u << 2));
  s2g_attn_mfma_kernel<<<dim3(L / 64, H, B), threads, 0, stream>>>(QBh, KGh, VGh, OBh);
  gemm(OBh, s2g_wo_t, s2g_bo, S1, S2, B * L, INNER, D, 0, 2, S2h);  // dual write f32+bf16

  // --- global -> spatial cross attention (ctx = updated spatial S2) ---
  ln_kernel<<<B * G, threads, 0, stream>>>(GL, gcn_g, gcn_b, GNh);
  gemm(GNh, g2s_wq_t, nullptr, nullptr, QGh, B * G, D, INNER, 0, 1, nullptr);
  gemm_multi(S2h, g2s_wk_t, g2s_wv_t, nullptr, nullptr, KBh, VBh, nullptr, nullptr, 2, B * L, D, INNER,
             1u | (1u << 2));
  g2s_vt_kernel<<<dim3(L / 32, INNER / 32, B), threads, 0, stream>>>(VBh, Vt);
  g2s_logits_kernel<<<dim3(L / 128, H, B), threads, 0, stream>>>(QGh, KBh, LG);
  g2s_softmax_kernel<<<B * G, threads, 0, stream>>>(LG, WG);
  g2s_pv_kernel<<<dim3(8, H, B), threads, 0, stream>>>(WG, Vt, Opart);
  g2s_combine_kernel<<<B * G, threads, 0, stream>>>(Opart, OGh);
  gemm(OGh, g2s_wo_t, g2s_bo, GL, G1, B * G, INNER, D, 0, 0, nullptr);

  // --- global FFN ---
  ln_kernel<<<B * G, threads, 0, stream>>>(G1, gfn_g, gfn_b, GNh);
  gemm(GNh, gff1_t, gff_b1, nullptr, HGh, B * G, D, FF, 1, 1, nullptr);
  gemm(HGh, gff2_t, gff_b2, G1, G2, B * G, FF, D, 0, 0, nullptr);

  // --- spatial FFN ---
  ln_kernel<<<B * L, threads, 0, stream>>>(S2, sfn_g, sfn_b, XNh);
  gemm(XNh, sff1_t, sff_b1, nullptr, HSh, B * L, D, FF, 1, 1, nullptr);
  gemm(HSh, sff2_t, sff_b2, S2, S1, B * L, FF, D, 0, 0, nullptr);

  assemble_kernel<<<nsplit, threads, 0, stream>>>(S1, G2, (float*)d_out);
}